// Round 12
// baseline (240.214 us; speedup 1.0000x reference)
//
#include <hip/hip_runtime.h>

#define NODES 16
#define TT    128   // tokens per utterance
#define DIM   256   // local feature dim
#define ATTD  128   // attention inner dim
#define HD    256   // hidden dim
#define NEGV  -1e9f
#define NBLK  256   // persistent grid size (<= capacity: 2 blocks/CU x 256 CU)

typedef short bf16x8 __attribute__((ext_vector_type(8)));
typedef float f32x4  __attribute__((ext_vector_type(4)));
typedef unsigned short ushort_t;
typedef ushort_t u16x4 __attribute__((ext_vector_type(4)));
typedef ushort_t u16x8 __attribute__((ext_vector_type(8)));

__device__ __forceinline__ ushort_t f2b(float f) {
  union { float f; unsigned u; } v; v.f = f;
  unsigned r = (v.u + 0x7fffu + ((v.u >> 16) & 1u)) >> 16;
  return (ushort_t)r;
}
__device__ __forceinline__ float b2f(ushort_t h) {
  union { unsigned u; float f; } v; v.u = ((unsigned)h) << 16; return v.f;
}

// ---- manual grid barrier: release-fence + device-scope counter + acquire ---
__device__ __forceinline__ void gbar(unsigned* __restrict__ ctr, int idx) {
  __syncthreads();
  if (threadIdx.x == 0) {
    __threadfence();                    // release: flush this block's writes
    atomicAdd(&ctr[idx], 1u);
    while (__hip_atomic_load(&ctr[idx], __ATOMIC_RELAXED,
                             __HIP_MEMORY_SCOPE_AGENT) < (unsigned)NBLK)
      __builtin_amdgcn_s_sleep(8);
    __threadfence();                    // acquire: invalidate stale L1/L2
  }
  __syncthreads();
}

// one K=32 step of a 64-row wave-tile GEMM from global; A row-major [.,as]
__device__ __forceinline__ void wave_gemm_step(const ushort_t* __restrict__ A, int as, int R0,
                                               const ushort_t* __restrict__ BT, int bs, int C0,
                                               int kb, int lr, f32x4 acc[4][4]) {
  bf16x8 a[4], b[4];
#pragma unroll
  for (int m = 0; m < 4; ++m)
    a[m] = *(const bf16x8*)(A + (size_t)(R0 + m * 16 + lr) * as + kb);
#pragma unroll
  for (int n = 0; n < 4; ++n)
    b[n] = *(const bf16x8*)(BT + (size_t)(C0 + n * 16 + lr) * bs + kb);
#pragma unroll
  for (int m = 0; m < 4; ++m)
#pragma unroll
    for (int n = 0; n < 4; ++n)
      acc[m][n] = __builtin_amdgcn_mfma_f32_16x16x32_bf16(a[m], b[n], acc[m][n], 0, 0, 0);
}

#define ACC_INIT(acc)                                 \
  f32x4 acc[4][4];                                    \
  { f32x4 z = {0.f, 0.f, 0.f, 0.f};                   \
    _Pragma("unroll") for (int m = 0; m < 4; ++m)     \
    _Pragma("unroll") for (int n = 0; n < 4; ++n) acc[m][n] = z; }

// ---- K-chunk LDS helpers: 128 rows x 64 bf16 (16 KB), 128B rows, swizzle ---
__device__ __forceinline__ void stage_half(const ushort_t* __restrict__ src, int srcs,
                                           ushort_t* __restrict__ dst, int tid) {
#pragma unroll
  for (int p = 0; p < 4; ++p) {
    int idx = p * 256 + tid;               // 1024 x 16B chunks
    int row = idx >> 3;                    // 8 chunks per row
    int cb  = (idx & 7) << 4;              // byte col within 128B row
    u16x8 v = *(const u16x8*)(src + (size_t)row * srcs + (cb >> 1));
    *(u16x8*)((char*)dst + row * 128 + (cb ^ ((row & 7) << 4))) = v;
  }
}

__device__ __forceinline__ void gemm_half(const ushort_t* __restrict__ bufA,
                                          const ushort_t* __restrict__ bufB,
                                          int R0, int C0, int lr, int kg,
                                          f32x4 acc[4][4]) {
#pragma unroll
  for (int kk = 0; kk < 2; ++kk) {
    int cb = kk * 64 + kg * 16;
    bf16x8 a[4], b[4];
#pragma unroll
    for (int m = 0; m < 4; ++m) {
      int row = R0 + m * 16 + lr;
      a[m] = *(const bf16x8*)((const char*)bufA + row * 128 + (cb ^ ((row & 7) << 4)));
    }
#pragma unroll
    for (int n = 0; n < 4; ++n) {
      int row = C0 + n * 16 + lr;
      b[n] = *(const bf16x8*)((const char*)bufB + row * 128 + (cb ^ ((row & 7) << 4)));
    }
#pragma unroll
    for (int m = 0; m < 4; ++m)
#pragma unroll
      for (int n = 0; n < 4; ++n)
        acc[m][n] = __builtin_amdgcn_mfma_f32_16x16x32_bf16(a[m], b[n], acc[m][n], 0, 0, 0);
  }
}

struct MegaParams {
  const float *Lf, *Wb1, *Wb2, *Wroot1, *Wroot2, *Wrel2, *Wrel1;
  const float *G, *Wq, *Wk, *vatt, *b1, *b2;
  const int *spk, *len;
  ushort_t *Lfh, *Wb1T, *Wb2T, *Wroot1T, *Wroot2T, *Wrel2T, *Wrel1T8;
  ushort_t *p1h, *p2h, *lwT, *YT, *x1h, *x1T, *Z2h, *partH;
  float *gw, *qk, *x1part, *out;
  unsigned *ctr;
};

union ShMem {
  ushort_t buf[2][16384];                              // 64 KB dbuf (A | B+8192)
  float S[TT][129];                                    // ~66 KB score matrix
  float tr[64][65];                                    // transpose tile
  struct { float sred[NODES][17]; float q[ATTD]; } sc; // global-att scratch
  ushort_t L[TT][40];                                  // reduce1 transpose tile
};

// ---- wagg phase body (shared by layer 1 / layer 2) -------------------------
__device__ __forceinline__ void wagg_phase(int bid, int tid, int wr, int wc,
                                           int lr, int kg, ShMem& sh,
                                           const ushort_t* __restrict__ lwT,
                                           const ushort_t* __restrict__ Bsrc,
                                           const float* __restrict__ gw,
                                           const int* __restrict__ spk,
                                           ushort_t* __restrict__ partH, int mode) {
  int g = bid >> 5, j = (bid >> 1) & 15, oh = bid & 1;
  int R0 = wr * 64, C0 = wc * 64;
  int i0 = g * 2, i1 = g * 2 + 1;
  int e0 = i0 * NODES + j, e1 = i1 * NODES + j;
  const ushort_t *B0, *B1;
  float ge0, ge1;
  if (mode == 1) {
    int q0 = spk[j] * 2 + ((i0 < j) ? 0 : 1);
    int q1 = spk[j] * 2 + ((i1 < j) ? 0 : 1);
    B0 = Bsrc + (size_t)(i0 * 4 + q0) * 32768 + (size_t)oh * 16384;
    B1 = Bsrc + (size_t)(i1 * 4 + q1) * 32768 + (size_t)oh * 16384;
    ge0 = gw[e0]; ge1 = gw[e1];
  } else {
    B0 = Bsrc + (size_t)i0 * 32768 + (size_t)oh * 16384;
    B1 = Bsrc + (size_t)i1 * 32768 + (size_t)oh * 16384;
    ge0 = 1.f; ge1 = 1.f;
  }
  const ushort_t* A0 = lwT + (size_t)e0 * 16384;
  const ushort_t* A1 = lwT + (size_t)e1 * 16384;
  stage_half(A0, TT, sh.buf[0], tid);
  stage_half(B0, TT, sh.buf[0] + 8192, tid);
  __syncthreads();
  stage_half(A0 + 64, TT, sh.buf[1], tid);
  stage_half(B0 + 64, TT, sh.buf[1] + 8192, tid);
  ACC_INIT(acc0)
  gemm_half(sh.buf[0], sh.buf[0] + 8192, R0, C0, lr, kg, acc0);
  __syncthreads();
  stage_half(A1, TT, sh.buf[0], tid);
  stage_half(B1, TT, sh.buf[0] + 8192, tid);
  gemm_half(sh.buf[1], sh.buf[1] + 8192, R0, C0, lr, kg, acc0);
  __syncthreads();
  stage_half(A1 + 64, TT, sh.buf[1], tid);
  stage_half(B1 + 64, TT, sh.buf[1] + 8192, tid);
  ACC_INIT(acc1)
  gemm_half(sh.buf[0], sh.buf[0] + 8192, R0, C0, lr, kg, acc1);
  __syncthreads();
  gemm_half(sh.buf[1], sh.buf[1] + 8192, R0, C0, lr, kg, acc1);
  size_t base = (size_t)(g * NODES + j) * TT * HD + (size_t)oh * 128;
#pragma unroll
  for (int m = 0; m < 4; ++m)
#pragma unroll
    for (int n = 0; n < 4; ++n) {
      int ocol = C0 + n * 16 + lr;
#pragma unroll
      for (int r = 0; r < 4; ++r) {
        int s = R0 + m * 16 + kg * 4 + r;
        partH[base + (size_t)s * HD + ocol] = f2b(ge0 * acc0[m][n][r] + ge1 * acc1[m][n][r]);
      }
    }
}

__global__ __launch_bounds__(256, 1)
void k_mega(MegaParams P) {
  __shared__ ShMem sh;
  __shared__ float red[TT][2];
  __shared__ float sInv[TT];
  const int bid = blockIdx.x;
  const int tid = threadIdx.x;
  const int wave = tid >> 6, lane = tid & 63;
  const int wr = wave >> 1, wc = wave & 1;
  const int lr = lane & 15, kg = lane >> 4;
  const size_t Q = (size_t)NODES * TT * HD;

  // ========== phase 0: cast Lf (all) + transpose W (0-191) + qk (192-207) ===
  {
    int gi = bid * 256 + tid;
    const float4* src = (const float4*)P.Lf;
    float4 v0 = src[gi * 2], v1 = src[gi * 2 + 1];
    u16x8 o;
    o[0] = f2b(v0.x); o[1] = f2b(v0.y); o[2] = f2b(v0.z); o[3] = f2b(v0.w);
    o[4] = f2b(v1.x); o[5] = f2b(v1.y); o[6] = f2b(v1.z); o[7] = f2b(v1.w);
    *(u16x8*)(P.Lfh + (size_t)gi * 8) = o;
  }
  if (bid < 192) {
    int b = bid;
    const float* src; ushort_t* dst; int C, t;
    if (b < 8)       { src = P.Wb1;    dst = P.Wb1T;    C = 128; t = b; }
    else if (b < 16) { src = P.Wb2;    dst = P.Wb2T;    C = 128; t = b - 8; }
    else if (b < 32) { src = P.Wroot1; dst = P.Wroot1T; C = 256; t = b - 16; }
    else if (b < 48) { src = P.Wroot2; dst = P.Wroot2T; C = 256; t = b - 32; }
    else if (b < 64) { src = P.Wrel2;  dst = P.Wrel2T;  C = 256; t = b - 48; }
    else {
      int m = (b - 64) >> 4;
      int relid = (m >> 2) * 32 + (m & 3);
      src = P.Wrel1 + (size_t)relid * 65536;
      dst = P.Wrel1T8 + (size_t)m * 65536;
      C = 256; t = (b - 64) & 15;
    }
    int tilesC = C >> 6;
    int r0 = (t / tilesC) * 64, c0 = (t % tilesC) * 64;
    for (int p = 0; p < 16; ++p) {
      int idx = p * 256 + tid, rr = idx >> 6, cc = idx & 63;
      sh.tr[rr][cc] = src[(size_t)(r0 + rr) * C + c0 + cc];
    }
    __syncthreads();
    for (int p = 0; p < 16; ++p) {
      int idx = p * 256 + tid, rr = idx >> 6, cc = idx & 63;
      dst[(size_t)(c0 + rr) * 256 + r0 + cc] = f2b(sh.tr[cc][rr]);
    }
  } else if (bid < 208) {
    int i = bid - 192;
    const float* W = (tid < 128) ? P.Wq : P.Wk;
    int a = tid & 127;
    float acc = 0.f;
#pragma unroll 8
    for (int d = 0; d < DIM; ++d)
      acc = fmaf(P.G[i * DIM + d], W[d * ATTD + a], acc);
    int dst = (tid < 128) ? i : (NODES + i);
    P.qk[(size_t)dst * ATTD + a] = acc;
  }
  gbar(P.ctr, 0);

  // ========== phase 1: score (0-15) + proj (16-47) + x1root (48-79) + Y =====
  if (bid < 16) {
    int i = bid;
    int j = tid >> 4, ag = tid & 15;
    if (tid < ATTD) sh.sc.q[tid] = P.qk[(size_t)i * ATTD + tid];
    __syncthreads();
    float sum = 0.f;
#pragma unroll
    for (int u = 0; u < 8; ++u) {
      int a = ag * 8 + u;
      sum += tanhf(sh.sc.q[a] + P.qk[(size_t)(NODES + j) * ATTD + a]) * P.vatt[a];
    }
    sh.sc.sred[j][ag] = sum;
    __syncthreads();
    if (tid < NODES) {
      float s = 0.f;
#pragma unroll
      for (int u = 0; u < 16; ++u) s += sh.sc.sred[tid][u];
      sh.sc.sred[tid][16] = s;
    }
    __syncthreads();
    if (tid == 0) {
      float m = -1e30f;
      for (int jj = 0; jj < NODES; ++jj) m = fmaxf(m, sh.sc.sred[jj][16]);
      float ex[NODES], ssum = 0.f;
      for (int jj = 0; jj < NODES; ++jj) { ex[jj] = __expf(sh.sc.sred[jj][16] - m); ssum += ex[jj]; }
      float inv = 1.f / ssum;
      for (int jj = 0; jj < NODES; ++jj) P.gw[i * NODES + jj] = ex[jj] * inv;
    }
  } else if (bid < 208) {
    const ushort_t *Asrc, *Bsrc;
    if (bid < 48) {
      int t = bid - 16; int sel = t >> 4, bx = t & 15;
      Asrc = P.Lfh + (size_t)bx * 128 * DIM;
      Bsrc = sel ? P.Wb2T : P.Wb1T;
    } else if (bid < 80) {
      int t = bid - 48; int bx = t & 15, by = t >> 4;
      Asrc = P.Lfh + (size_t)bx * 128 * DIM;
      Bsrc = P.Wroot1T + (size_t)by * 128 * DIM;
    } else {
      int t = bid - 80; int iq = t >> 1, cy = t & 1;
      int i = iq >> 2, q = iq & 3;
      int m8 = P.spk[i] * 4 + q;
      Asrc = P.Lfh + (size_t)i * TT * DIM;
      Bsrc = P.Wrel1T8 + (size_t)m8 * 65536 + (size_t)cy * 128 * DIM;
    }
    stage_half(Asrc, DIM, sh.buf[0], tid);
    stage_half(Bsrc, DIM, sh.buf[0] + 8192, tid);
    __syncthreads();
    ACC_INIT(acc)
    for (int c = 1; c < 4; ++c) {
      stage_half(Asrc + c * 64, DIM, sh.buf[c & 1], tid);
      stage_half(Bsrc + c * 64, DIM, sh.buf[c & 1] + 8192, tid);
      gemm_half(sh.buf[(c & 1) ^ 1], sh.buf[(c & 1) ^ 1] + 8192, wr * 64, wc * 64, lr, kg, acc);
      __syncthreads();
    }
    gemm_half(sh.buf[1], sh.buf[1] + 8192, wr * 64, wc * 64, lr, kg, acc);
    if (bid < 48) {
      int t = bid - 16; int sel = t >> 4, bx = t & 15;
      ushort_t* out = sel ? P.p2h : P.p1h;
      int R0 = bx * 128 + wr * 64, C0 = wc * 64;
#pragma unroll
      for (int m = 0; m < 4; ++m)
#pragma unroll
        for (int n = 0; n < 4; ++n) {
          int col = C0 + n * 16 + lr;
#pragma unroll
          for (int r = 0; r < 4; ++r) {
            int row = R0 + m * 16 + kg * 4 + r;
            out[(size_t)row * ATTD + col] = f2b(acc[m][n][r]);
          }
        }
    } else if (bid < 80) {
      int t = bid - 48; int bx = t & 15, by = t >> 4;
      int R0 = bx * 128 + wr * 64, C0 = by * 128 + wc * 64;
#pragma unroll
      for (int m = 0; m < 4; ++m)
#pragma unroll
        for (int n = 0; n < 4; ++n) {
          int col = C0 + n * 16 + lr;
          float bb = P.b1[col];
#pragma unroll
          for (int r = 0; r < 4; ++r) {
            int row = R0 + m * 16 + kg * 4 + r;
            P.x1part[(size_t)row * HD + col] = acc[m][n][r] + bb;
          }
        }
    } else {
      int t = bid - 80; int iq = t >> 1, cy = t & 1;
      int R0 = wr * 64, C0 = cy * 128 + wc * 64;
#pragma unroll
      for (int m = 0; m < 4; ++m)
#pragma unroll
        for (int n = 0; n < 4; ++n) {
          int o = C0 + n * 16 + lr;
          int t0 = R0 + m * 16 + kg * 4;
          u16x4 v;
#pragma unroll
          for (int r = 0; r < 4; ++r) v[r] = f2b(acc[m][n][r]);
          *(u16x4*)(P.YT + (size_t)iq * 32768 + (size_t)o * TT + t0) = v;
        }
    }
  }
  gbar(P.ctr, 1);

  // ========== phase 2: per-edge local attention -> lwT ======================
  {
    int e = bid, i = e >> 4, j = e & 15;
    int R0 = wr * 64, C0 = wc * 64;
    const ushort_t* A = P.p1h + (size_t)i * TT * ATTD;
    const ushort_t* B = P.p2h + (size_t)j * TT * ATTD;
    stage_half(A, ATTD, sh.buf[0], tid);
    stage_half(B, ATTD, sh.buf[0] + 8192, tid);
    __syncthreads();
    stage_half(A + 64, ATTD, sh.buf[1], tid);
    stage_half(B + 64, ATTD, sh.buf[1] + 8192, tid);
    ACC_INIT(acc)
    gemm_half(sh.buf[0], sh.buf[0] + 8192, R0, C0, lr, kg, acc);
    __syncthreads();
    gemm_half(sh.buf[1], sh.buf[1] + 8192, R0, C0, lr, kg, acc);
    __syncthreads();           // all waves done with buf before S overwrites
#pragma unroll
    for (int m = 0; m < 4; ++m)
#pragma unroll
      for (int n = 0; n < 4; ++n)
#pragma unroll
        for (int r = 0; r < 4; ++r)
          sh.S[R0 + m * 16 + kg * 4 + r][C0 + n * 16 + lr] = acc[m][n][r];
    __syncthreads();
    int leni = P.len[i], lenj = P.len[j];
    int t = tid & 127, h = tid >> 7, s0 = h * 64;
    float mx = -1e30f;
    for (int s = s0; s < s0 + 64; ++s) {
      float vv = (s < lenj) ? sh.S[t][s] : NEGV;
      mx = fmaxf(mx, vv);
    }
    red[t][h] = mx;
    __syncthreads();
    mx = fmaxf(red[t][0], red[t][1]);
    __syncthreads();
    float sum = 0.f;
    for (int s = s0; s < s0 + 64; ++s) {
      float vv = (s < lenj) ? sh.S[t][s] : NEGV;
      float ee = __expf(vv - mx);
      sh.S[t][s] = ee;
      sum += ee;
    }
    red[t][h] = sum;
    __syncthreads();
    if (h == 0) sInv[t] = (t < leni) ? 1.f / (red[t][0] + red[t][1]) : 0.f;
    __syncthreads();
    int s = tid >> 1;
    int t0 = (tid & 1) * 64;
    size_t base = (size_t)e * 16384 + (size_t)s * TT;
    for (int tb = 0; tb < 64; tb += 8) {
      u16x8 w;
#pragma unroll
      for (int u = 0; u < 8; ++u) {
        int tt = t0 + tb + u;
        w[u] = f2b(sh.S[tt][s] * sInv[tt]);
      }
      *(u16x8*)(P.lwT + base + t0 + tb) = w;
    }
  }
  gbar(P.ctr, 2);

  // ========== phase 3: wagg layer-1 -> partH ================================
  wagg_phase(bid, tid, wr, wc, lr, kg, sh, P.lwT, P.YT, P.gw, P.spk, P.partH, 1);
  gbar(P.ctr, 3);

  // ========== phase 4: reduce1 -> x1h + x1T (blocks 0-127) ==================
  if (bid < 128) {
    int j = bid >> 3, oc0 = (bid & 7) * 32;
#pragma unroll
    for (int p = 0; p < 4; ++p) {
      int idx = p * 256 + tid;
      int t = idx >> 3, o4 = (idx & 7) * 4;
      size_t goff = ((size_t)j * TT + t) * HD + oc0 + o4;
      float4 s = *(const float4*)(P.x1part + goff);
#pragma unroll
      for (int g = 0; g < 8; ++g) {
        u16x4 pv = *(const u16x4*)(P.partH + (size_t)g * Q + goff);
        s.x += b2f(pv[0]); s.y += b2f(pv[1]); s.z += b2f(pv[2]); s.w += b2f(pv[3]);
      }
      u16x4 hv; hv[0] = f2b(s.x); hv[1] = f2b(s.y); hv[2] = f2b(s.z); hv[3] = f2b(s.w);
      *(u16x4*)(P.x1h + goff) = hv;
      *(u16x4*)(&sh.L[t][o4]) = hv;
    }
    __syncthreads();
#pragma unroll
    for (int p = 0; p < 2; ++p) {
      int idx = p * 256 + tid;
      int o = idx >> 4, t8 = (idx & 15) * 8;
      u16x8 v;
#pragma unroll
      for (int u = 0; u < 8; ++u) v[u] = sh.L[t8 + u][o];
      *(u16x8*)(P.x1T + (size_t)j * 32768 + (size_t)(oc0 + o) * TT + t8) = v;
    }
  }
  gbar(P.ctr, 4);

  // ========== phase 5: wagg layer-2 -> partH ================================
  wagg_phase(bid, tid, wr, wc, lr, kg, sh, P.lwT, P.x1T, P.gw, P.spk, P.partH, 2);
  gbar(P.ctr, 5);

  // ========== phase 6: reduce2 -> Z2h =======================================
#pragma unroll
  for (int pass = 0; pass < 2; ++pass) {
    int idx = (pass * 256 + bid) * 256 + tid;
    size_t o4 = (size_t)idx * 4;
    float4 s = {0.f, 0.f, 0.f, 0.f};
#pragma unroll
    for (int g = 0; g < 8; ++g) {
      u16x4 pv = *(const u16x4*)(P.partH + (size_t)g * Q + o4);
      s.x += b2f(pv[0]); s.y += b2f(pv[1]); s.z += b2f(pv[2]); s.w += b2f(pv[3]);
    }
    u16x4 hv; hv[0] = f2b(s.x); hv[1] = f2b(s.y); hv[2] = f2b(s.z); hv[3] = f2b(s.w);
    *(u16x4*)(P.Z2h + o4) = hv;
  }
  gbar(P.ctr, 6);

  // ========== phase 7: out = Z2h@Wrel2 + x1h@Wroot2 + b2 (blocks 0-63) ======
  if (bid < 64) {
    int R0 = (bid & 31) * 64;
    int C0 = (bid >> 5) * 128 + wave * 32;
    f32x4 acc[4][2];
    { f32x4 z = {0.f, 0.f, 0.f, 0.f};
#pragma unroll
      for (int m = 0; m < 4; ++m)
#pragma unroll
        for (int n = 0; n < 2; ++n) acc[m][n] = z; }
    for (int src = 0; src < 2; ++src) {
      const ushort_t* A  = src ? P.x1h : P.Z2h;
      const ushort_t* BT = src ? P.Wroot2T : P.Wrel2T;
      for (int kk = 0; kk < 8; ++kk) {
        int kb = kk * 32 + kg * 8;
        bf16x8 a[4], b[2];
#pragma unroll
        for (int m = 0; m < 4; ++m)
          a[m] = *(const bf16x8*)(A + (size_t)(R0 + m * 16 + lr) * HD + kb);
#pragma unroll
        for (int n = 0; n < 2; ++n)
          b[n] = *(const bf16x8*)(BT + (size_t)(C0 + n * 16 + lr) * HD + kb);
#pragma unroll
        for (int m = 0; m < 4; ++m)
#pragma unroll
          for (int n = 0; n < 2; ++n)
            acc[m][n] = __builtin_amdgcn_mfma_f32_16x16x32_bf16(a[m], b[n], acc[m][n], 0, 0, 0);
      }
    }
#pragma unroll
    for (int m = 0; m < 4; ++m)
#pragma unroll
      for (int n = 0; n < 2; ++n) {
        int col = C0 + n * 16 + lr;
        float bb = P.b2[col];
#pragma unroll
        for (int r = 0; r < 4; ++r) {
          int row = R0 + m * 16 + kg * 4 + r;
          P.out[(size_t)row * HD + col] = acc[m][n][r] + bb;
        }
      }
  }
}

extern "C" void kernel_launch(void* const* d_in, const int* in_sizes, int n_in,
                              void* d_out, int out_size, void* d_ws, size_t ws_size,
                              hipStream_t stream) {
  (void)in_sizes; (void)n_in; (void)out_size; (void)ws_size;
  char* ws = (char*)d_ws;
  const size_t MB = 1ull << 20;

  MegaParams P;
  P.G      = (const float*)d_in[0];
  P.Lf     = (const float*)d_in[1];
  P.spk    = (const int*)d_in[2];
  P.len    = (const int*)d_in[3];
  P.Wq     = (const float*)d_in[4];
  P.Wk     = (const float*)d_in[5];
  P.vatt   = (const float*)d_in[6];
  P.Wb1    = (const float*)d_in[7];
  P.Wb2    = (const float*)d_in[8];
  P.Wrel1  = (const float*)d_in[9];
  P.Wroot1 = (const float*)d_in[10];
  P.b1     = (const float*)d_in[11];
  P.Wrel2  = (const float*)d_in[12];
  P.Wroot2 = (const float*)d_in[13];
  P.b2     = (const float*)d_in[14];

  P.gw      = (float*)(ws);
  P.qk      = (float*)(ws + 16 * 1024);
  P.Lfh     = (ushort_t*)(ws + 1 * MB);
  P.Wb1T    = (ushort_t*)(ws + 2 * MB);
  P.Wb2T    = (ushort_t*)(ws + 2 * MB + 64 * 1024);
  P.Wroot1T = (ushort_t*)(ws + 2 * MB + 128 * 1024);
  P.Wroot2T = (ushort_t*)(ws + 2 * MB + 256 * 1024);
  P.Wrel2T  = (ushort_t*)(ws + 2 * MB + 384 * 1024);
  P.Wrel1T8 = (ushort_t*)(ws + 2 * MB + 512 * 1024);  // 1 MB
  P.p1h     = (ushort_t*)(ws + 4 * MB);
  P.p2h     = (ushort_t*)(ws + 4 * MB + 512 * 1024);
  P.lwT     = (ushort_t*)(ws + 5 * MB);    // 8 MB
  P.YT      = (ushort_t*)(ws + 21 * MB);   // 4 MB
  P.x1part  = (float*)(ws + 25 * MB);      // 2 MB
  P.partH   = (ushort_t*)(ws + 27 * MB);   // 8 MB (8 groups, bf16)
  P.x1h     = (ushort_t*)(ws + 43 * MB);   // 1 MB
  P.x1T     = (ushort_t*)(ws + 44 * MB);   // 1 MB
  P.Z2h     = (ushort_t*)(ws + 45 * MB);   // 1 MB
  P.ctr     = (unsigned*)(ws + 47 * MB);   // 7 barrier counters
  P.out     = (float*)d_out;

  // reset barrier counters every call (capturable; keeps launches deterministic)
  hipMemsetAsync(P.ctr, 0, 64, stream);
  k_mega<<<NBLK, 256, 0, stream>>>(P);
}

// Round 13
// 75.781 us; speedup vs baseline: 3.1698x; 3.1698x over previous
//
#include <hip/hip_runtime.h>

#define NODES 16
#define TT    128   // tokens per utterance
#define DIM   256   // local feature dim
#define ATTD  128   // attention inner dim
#define HD    256   // hidden dim
#define NEGV  -1e9f

typedef short bf16x8 __attribute__((ext_vector_type(8)));
typedef float f32x4  __attribute__((ext_vector_type(4)));
typedef unsigned short ushort_t;
typedef ushort_t u16x4 __attribute__((ext_vector_type(4)));
typedef ushort_t u16x8 __attribute__((ext_vector_type(8)));

__device__ __forceinline__ ushort_t f2b(float f) {
  union { float f; unsigned u; } v; v.f = f;
  unsigned r = (v.u + 0x7fffu + ((v.u >> 16) & 1u)) >> 16;
  return (ushort_t)r;
}
__device__ __forceinline__ float b2f(ushort_t h) {
  union { unsigned u; float f; } v; v.u = ((unsigned)h) << 16; return v.f;
}

#define WAVE_SETUP                                    \
  int tid = threadIdx.x;                              \
  int wave = tid >> 6, lane = tid & 63;               \
  int wr = wave >> 1, wc = wave & 1;                  \
  int lr = lane & 15, kg = lane >> 4;                 \
  (void)wr; (void)wc;

#define ACC_INIT(acc)                                 \
  f32x4 acc[4][4];                                    \
  { f32x4 z = {0.f, 0.f, 0.f, 0.f};                   \
    _Pragma("unroll") for (int m = 0; m < 4; ++m)     \
    _Pragma("unroll") for (int n = 0; n < 4; ++n) acc[m][n] = z; }

// ---- K-chunk LDS helpers: 128 rows x 64 bf16 (16 KB), 128B rows, swizzle ---
__device__ __forceinline__ void stage_half(const ushort_t* __restrict__ src, int srcs,
                                           ushort_t* __restrict__ dst, int tid) {
#pragma unroll
  for (int p = 0; p < 4; ++p) {
    int idx = p * 256 + tid;               // 1024 x 16B chunks
    int row = idx >> 3;                    // 8 chunks per row
    int cb  = (idx & 7) << 4;              // byte col within 128B row
    u16x8 v = *(const u16x8*)(src + (size_t)row * srcs + (cb >> 1));
    *(u16x8*)((char*)dst + row * 128 + (cb ^ ((row & 7) << 4))) = v;
  }
}

__device__ __forceinline__ void gemm_half(const ushort_t* __restrict__ bufA,
                                          const ushort_t* __restrict__ bufB,
                                          int R0, int C0, int lr, int kg,
                                          f32x4 acc[4][4]) {
#pragma unroll
  for (int kk = 0; kk < 2; ++kk) {
    int cb = kk * 64 + kg * 16;
    bf16x8 a[4], b[4];
#pragma unroll
    for (int m = 0; m < 4; ++m) {
      int row = R0 + m * 16 + lr;
      a[m] = *(const bf16x8*)((const char*)bufA + row * 128 + (cb ^ ((row & 7) << 4)));
    }
#pragma unroll
    for (int n = 0; n < 4; ++n) {
      int row = C0 + n * 16 + lr;
      b[n] = *(const bf16x8*)((const char*)bufB + row * 128 + (cb ^ ((row & 7) << 4)));
    }
#pragma unroll
    for (int m = 0; m < 4; ++m)
#pragma unroll
      for (int n = 0; n < 4; ++n)
        acc[m][n] = __builtin_amdgcn_mfma_f32_16x16x32_bf16(a[m], b[n], acc[m][n], 0, 0, 0);
  }
}

// ============ K_PREP: cast Lf (256) + transpose weights (192) + qk (16) =====
__global__ void k_prep(const float* __restrict__ Lf, ushort_t* __restrict__ Lfh,
                       const float* __restrict__ Wb1, const float* __restrict__ Wb2,
                       const float* __restrict__ Wroot1, const float* __restrict__ Wroot2,
                       const float* __restrict__ Wrel2, const float* __restrict__ Wrel1,
                       ushort_t* __restrict__ Wb1T, ushort_t* __restrict__ Wb2T,
                       ushort_t* __restrict__ Wroot1T, ushort_t* __restrict__ Wroot2T,
                       ushort_t* __restrict__ Wrel2T, ushort_t* __restrict__ Wrel1T8,
                       const float* __restrict__ G, const float* __restrict__ Wq,
                       const float* __restrict__ Wk, float* __restrict__ qk) {
  int blk = blockIdx.x;
  if (blk < 256) {                       // ---- cast local_features to bf16
    int gi = blk * 256 + threadIdx.x;
    const float4* src = (const float4*)Lf;
    float4 v0 = src[gi * 2], v1 = src[gi * 2 + 1];
    u16x8 o;
    o[0] = f2b(v0.x); o[1] = f2b(v0.y); o[2] = f2b(v0.z); o[3] = f2b(v0.w);
    o[4] = f2b(v1.x); o[5] = f2b(v1.y); o[6] = f2b(v1.z); o[7] = f2b(v1.w);
    *(u16x8*)(Lfh + (size_t)gi * 8) = o;
  } else if (blk < 448) {                // ---- cast+transpose weights
    __shared__ float lds[64][65];
    int b = blk - 256;
    const float* src; ushort_t* dst; int C, t;
    if (b < 8)       { src = Wb1;    dst = Wb1T;    C = 128; t = b; }
    else if (b < 16) { src = Wb2;    dst = Wb2T;    C = 128; t = b - 8; }
    else if (b < 32) { src = Wroot1; dst = Wroot1T; C = 256; t = b - 16; }
    else if (b < 48) { src = Wroot2; dst = Wroot2T; C = 256; t = b - 32; }
    else if (b < 64) { src = Wrel2;  dst = Wrel2T;  C = 256; t = b - 48; }
    else {
      int m = (b - 64) >> 4;                 // 0..7 -> spk_i*4 + q
      int relid = (m >> 2) * 32 + (m & 3);   // (spk_i*16 + spk_j)*2 + dir
      src = Wrel1 + (size_t)relid * 65536;
      dst = Wrel1T8 + (size_t)m * 65536;
      C = 256; t = (b - 64) & 15;
    }
    int tilesC = C >> 6;
    int r0 = (t / tilesC) * 64, c0 = (t % tilesC) * 64;
    int tid = threadIdx.x;
    for (int p = 0; p < 16; ++p) {
      int idx = p * 256 + tid, rr = idx >> 6, cc = idx & 63;
      lds[rr][cc] = src[(size_t)(r0 + rr) * C + c0 + cc];
    }
    __syncthreads();
    for (int p = 0; p < 16; ++p) {
      int idx = p * 256 + tid, rr = idx >> 6, cc = idx & 63;
      dst[(size_t)(c0 + rr) * 256 + r0 + cc] = f2b(lds[cc][rr]);
    }
  } else {                               // ---- q/k projections for global att
    int i = blk - 448, t = threadIdx.x;
    const float* W = (t < 128) ? Wq : Wk;
    int a = t & 127;
    float acc = 0.f;
#pragma unroll 8
    for (int d = 0; d < DIM; ++d)
      acc = fmaf(G[i * DIM + d], W[d * ATTD + a], acc);
    int dst = (t < 128) ? i : (NODES + i);
    qk[(size_t)dst * ATTD + a] = acc;
  }
}

// ===== K_PHASEB: score (16) + proj (32) + x1root (32) + y (128) = 208 =======
// GEMM branches: K=256 as 4 chunks, 64 KB dbuf -> 2 blocks/CU
__global__ __launch_bounds__(256, 1)
void k_phaseB(const float* __restrict__ qk, const float* __restrict__ vatt,
              float* __restrict__ gw,
              const ushort_t* __restrict__ Lfh,
              const ushort_t* __restrict__ Wb1T, const ushort_t* __restrict__ Wb2T,
              ushort_t* __restrict__ p1h, ushort_t* __restrict__ p2h,
              const ushort_t* __restrict__ Wroot1T, const float* __restrict__ b1,
              float* __restrict__ x1part,
              const ushort_t* __restrict__ Wrel1T8, const int* __restrict__ spk,
              ushort_t* __restrict__ YT) {
  __shared__ union {
    ushort_t buf[2][16384];                         // 64 KB dbuf (A | B at +8192)
    struct { float sred[NODES][17]; float q[ATTD]; } sc;
  } sh;
  int blk = blockIdx.x;
  if (blk < 16) {                        // ---- global attention scores+softmax
    int i = blk, t = threadIdx.x;
    int j = t >> 4, ag = t & 15;
    if (t < ATTD) sh.sc.q[t] = qk[(size_t)i * ATTD + t];
    __syncthreads();
    float sum = 0.f;
#pragma unroll
    for (int u = 0; u < 8; ++u) {
      int a = ag * 8 + u;
      sum += tanhf(sh.sc.q[a] + qk[(size_t)(NODES + j) * ATTD + a]) * vatt[a];
    }
    sh.sc.sred[j][ag] = sum;
    __syncthreads();
    if (t < NODES) {
      float s = 0.f;
#pragma unroll
      for (int u = 0; u < 16; ++u) s += sh.sc.sred[t][u];
      sh.sc.sred[t][16] = s;
    }
    __syncthreads();
    if (t == 0) {
      float m = -1e30f;
      for (int jj = 0; jj < NODES; ++jj) m = fmaxf(m, sh.sc.sred[jj][16]);
      float ex[NODES], ssum = 0.f;
      for (int jj = 0; jj < NODES; ++jj) { ex[jj] = __expf(sh.sc.sred[jj][16] - m); ssum += ex[jj]; }
      float inv = 1.f / ssum;
      for (int jj = 0; jj < NODES; ++jj) gw[i * NODES + jj] = ex[jj] * inv;
    }
    return;
  }
  // ---- common K=256 dbuf GEMM for the three matmul branches ----
  WAVE_SETUP
  const ushort_t* Asrc; const ushort_t* Bsrc;
  if (blk < 48) {
    int t = blk - 16; int sel = t >> 4, bx = t & 15;
    Asrc = Lfh + (size_t)bx * 128 * DIM;
    Bsrc = sel ? Wb2T : Wb1T;
  } else if (blk < 80) {
    int t = blk - 48; int bx = t & 15, by = t >> 4;
    Asrc = Lfh + (size_t)bx * 128 * DIM;
    Bsrc = Wroot1T + (size_t)by * 128 * DIM;
  } else {
    int t = blk - 80; int iq = t >> 1, cy = t & 1;
    int i = iq >> 2, q = iq & 3;
    int m8 = spk[i] * 4 + q;
    Asrc = Lfh + (size_t)i * TT * DIM;
    Bsrc = Wrel1T8 + (size_t)m8 * 65536 + (size_t)cy * 128 * DIM;
  }
  stage_half(Asrc, DIM, sh.buf[0], tid);
  stage_half(Bsrc, DIM, sh.buf[0] + 8192, tid);
  __syncthreads();
  ACC_INIT(acc)
  for (int c = 1; c < 4; ++c) {
    stage_half(Asrc + c * 64, DIM, sh.buf[c & 1], tid);
    stage_half(Bsrc + c * 64, DIM, sh.buf[c & 1] + 8192, tid);
    gemm_half(sh.buf[(c & 1) ^ 1], sh.buf[(c & 1) ^ 1] + 8192, wr * 64, wc * 64, lr, kg, acc);
    __syncthreads();
  }
  gemm_half(sh.buf[1], sh.buf[1] + 8192, wr * 64, wc * 64, lr, kg, acc);
  // ---- branch-specific epilogue ----
  if (blk < 48) {
    int t = blk - 16; int sel = t >> 4, bx = t & 15;
    ushort_t* out = sel ? p2h : p1h;
    int R0 = bx * 128 + wr * 64, C0 = wc * 64;
#pragma unroll
    for (int m = 0; m < 4; ++m)
#pragma unroll
      for (int n = 0; n < 4; ++n) {
        int col = C0 + n * 16 + lr;
#pragma unroll
        for (int r = 0; r < 4; ++r) {
          int row = R0 + m * 16 + kg * 4 + r;
          out[(size_t)row * ATTD + col] = f2b(acc[m][n][r]);
        }
      }
  } else if (blk < 80) {
    int t = blk - 48; int bx = t & 15, by = t >> 4;
    int R0 = bx * 128 + wr * 64, C0 = by * 128 + wc * 64;
#pragma unroll
    for (int m = 0; m < 4; ++m)
#pragma unroll
      for (int n = 0; n < 4; ++n) {
        int col = C0 + n * 16 + lr;
        float bb = b1[col];
#pragma unroll
        for (int r = 0; r < 4; ++r) {
          int row = R0 + m * 16 + kg * 4 + r;
          x1part[(size_t)row * HD + col] = acc[m][n][r] + bb;
        }
      }
  } else {
    int t = blk - 80; int iq = t >> 1, cy = t & 1;
    int R0 = wr * 64, C0 = cy * 128 + wc * 64;
#pragma unroll
    for (int m = 0; m < 4; ++m)
#pragma unroll
      for (int n = 0; n < 4; ++n) {
        int o = C0 + n * 16 + lr;
        int t0 = R0 + m * 16 + kg * 4;
        u16x4 v;
#pragma unroll
        for (int r = 0; r < 4; ++r) v[r] = f2b(acc[m][n][r]);
        *(u16x4*)(YT + (size_t)iq * 32768 + (size_t)o * TT + t0) = v;
      }
  }
}

// ---------------- per-edge local attention -> lwT (bf16) --------------------
// grid = 256 blocks; K=128 as 2 chunks, S unions stage buf -> 2 blocks/CU
__global__ __launch_bounds__(256, 1)
void k_locatt(const ushort_t* __restrict__ p1h, const ushort_t* __restrict__ p2h,
              const int* __restrict__ length,
              ushort_t* __restrict__ lwT) {
  __shared__ union {
    ushort_t buf[2][16384];   // 64 KB dbuf
    float S[TT][129];         // ~66 KB score matrix (reused after gemm)
  } sh;
  __shared__ float red[TT][2];
  __shared__ float sInv[TT];
  int e = blockIdx.x, i = e >> 4, j = e & 15;
  WAVE_SETUP
  int R0 = wr * 64, C0 = wc * 64;
  const ushort_t* A = p1h + (size_t)i * TT * ATTD;
  const ushort_t* B = p2h + (size_t)j * TT * ATTD;
  stage_half(A, ATTD, sh.buf[0], tid);
  stage_half(B, ATTD, sh.buf[0] + 8192, tid);
  __syncthreads();
  stage_half(A + 64, ATTD, sh.buf[1], tid);
  stage_half(B + 64, ATTD, sh.buf[1] + 8192, tid);
  ACC_INIT(acc)
  gemm_half(sh.buf[0], sh.buf[0] + 8192, R0, C0, lr, kg, acc);
  __syncthreads();
  gemm_half(sh.buf[1], sh.buf[1] + 8192, R0, C0, lr, kg, acc);
  __syncthreads();           // all waves done reading buf before S overwrites
#pragma unroll
  for (int m = 0; m < 4; ++m)
#pragma unroll
    for (int n = 0; n < 4; ++n)
#pragma unroll
      for (int r = 0; r < 4; ++r)
        sh.S[R0 + m * 16 + kg * 4 + r][C0 + n * 16 + lr] = acc[m][n][r];
  __syncthreads();
  int leni = length[i], lenj = length[j];
  int t = tid & 127, h = tid >> 7, s0 = h * 64;
  float mx = -1e30f;
  for (int s = s0; s < s0 + 64; ++s) {
    float vv = (s < lenj) ? sh.S[t][s] : NEGV;
    mx = fmaxf(mx, vv);
  }
  red[t][h] = mx;
  __syncthreads();
  mx = fmaxf(red[t][0], red[t][1]);
  __syncthreads();
  float sum = 0.f;
  for (int s = s0; s < s0 + 64; ++s) {
    float vv = (s < lenj) ? sh.S[t][s] : NEGV;
    float ee = __expf(vv - mx);
    sh.S[t][s] = ee;
    sum += ee;
  }
  red[t][h] = sum;
  __syncthreads();
  if (h == 0) sInv[t] = (t < leni) ? 1.f / (red[t][0] + red[t][1]) : 0.f;
  __syncthreads();
  // transposed write: lwT[e][s][t]
  int s = tid >> 1;
  int t0 = (tid & 1) * 64;
  size_t base = (size_t)e * 16384 + (size_t)s * TT;
  for (int tb = 0; tb < 64; tb += 8) {
    u16x8 w;
#pragma unroll
    for (int u = 0; u < 8; ++u) {
      int tt = t0 + tb + u;
      w[u] = f2b(sh.S[tt][s] * sInv[tt]);
    }
    *(u16x8*)(lwT + base + t0 + tb) = w;
  }
}

// ---------------- weighted aggregation (dbuf K-chunk transpose-GEMM) --------
// partH[g][j][s][o] = bf16( sum_{i in group g} ge_i * (lwT[e]^T-contract) )
// grid = (8, 16, 2); 64 KB LDS -> 2 blocks/CU
__global__ __launch_bounds__(256, 1)
void k_wagg(const ushort_t* __restrict__ lwT, const ushort_t* __restrict__ Bsrc,
            const float* __restrict__ gw, const int* __restrict__ spk,
            ushort_t* __restrict__ partH, int mode) {
  __shared__ ushort_t buf[2][16384];     // 64 KB dbuf (A | B at +8192)
  int g = blockIdx.x, j = blockIdx.y, oh = blockIdx.z;
  WAVE_SETUP
  int R0 = wr * 64, C0 = wc * 64;
  int i0 = g * 2, i1 = g * 2 + 1;
  int e0 = i0 * NODES + j, e1 = i1 * NODES + j;
  const ushort_t* B0;
  const ushort_t* B1;
  float ge0, ge1;
  if (mode == 1) {
    int q0 = spk[j] * 2 + ((i0 < j) ? 0 : 1);
    int q1 = spk[j] * 2 + ((i1 < j) ? 0 : 1);
    B0 = Bsrc + (size_t)(i0 * 4 + q0) * 32768 + (size_t)oh * 16384;
    B1 = Bsrc + (size_t)(i1 * 4 + q1) * 32768 + (size_t)oh * 16384;
    ge0 = gw[e0]; ge1 = gw[e1];
  } else {
    B0 = Bsrc + (size_t)i0 * 32768 + (size_t)oh * 16384;
    B1 = Bsrc + (size_t)i1 * 32768 + (size_t)oh * 16384;
    ge0 = 1.f; ge1 = 1.f;
  }
  const ushort_t* A0 = lwT + (size_t)e0 * 16384;
  const ushort_t* A1 = lwT + (size_t)e1 * 16384;
  stage_half(A0, TT, buf[0], tid);
  stage_half(B0, TT, buf[0] + 8192, tid);
  __syncthreads();
  stage_half(A0 + 64, TT, buf[1], tid);
  stage_half(B0 + 64, TT, buf[1] + 8192, tid);
  ACC_INIT(acc0)
  gemm_half(buf[0], buf[0] + 8192, R0, C0, lr, kg, acc0);
  __syncthreads();
  stage_half(A1, TT, buf[0], tid);
  stage_half(B1, TT, buf[0] + 8192, tid);
  gemm_half(buf[1], buf[1] + 8192, R0, C0, lr, kg, acc0);
  __syncthreads();
  stage_half(A1 + 64, TT, buf[1], tid);
  stage_half(B1 + 64, TT, buf[1] + 8192, tid);
  ACC_INIT(acc1)
  gemm_half(buf[0], buf[0] + 8192, R0, C0, lr, kg, acc1);
  __syncthreads();
  gemm_half(buf[1], buf[1] + 8192, R0, C0, lr, kg, acc1);
  size_t base = (size_t)(g * NODES + j) * TT * HD + (size_t)oh * 128;
#pragma unroll
  for (int m = 0; m < 4; ++m)
#pragma unroll
    for (int n = 0; n < 4; ++n) {
      int ocol = C0 + n * 16 + lr;
#pragma unroll
      for (int r = 0; r < 4; ++r) {
        int s = R0 + m * 16 + kg * 4 + r;
        partH[base + (size_t)s * HD + ocol] = f2b(ge0 * acc0[m][n][r] + ge1 * acc1[m][n][r]);
      }
    }
}

// ---------------- reduce layer-1 partials -> x1h (bf16) + x1T (bf16) --------
// grid = (16, 8): (node j, 32-col o-block); sums 8 bf16 groups + f32 root term
__global__ __launch_bounds__(256, 1)
void k_reduce1(const ushort_t* __restrict__ partH, const float* __restrict__ x1part,
               ushort_t* __restrict__ x1h, ushort_t* __restrict__ x1T) {
  __shared__ ushort_t L[TT][40];   // [t][o], padded
  int j = blockIdx.x, oc0 = blockIdx.y * 32, tid = threadIdx.x;
  const size_t Q = (size_t)NODES * TT * HD;  // 524288 per group
#pragma unroll
  for (int p = 0; p < 4; ++p) {
    int idx = p * 256 + tid;          // 1024 quads: 128 t x 8
    int t = idx >> 3, o4 = (idx & 7) * 4;
    size_t goff = ((size_t)j * TT + t) * HD + oc0 + o4;
    float4 s = *(const float4*)(x1part + goff);
#pragma unroll
    for (int g = 0; g < 8; ++g) {
      u16x4 pv = *(const u16x4*)(partH + (size_t)g * Q + goff);
      s.x += b2f(pv[0]); s.y += b2f(pv[1]); s.z += b2f(pv[2]); s.w += b2f(pv[3]);
    }
    u16x4 hv; hv[0] = f2b(s.x); hv[1] = f2b(s.y); hv[2] = f2b(s.z); hv[3] = f2b(s.w);
    *(u16x4*)(x1h + goff) = hv;
    *(u16x4*)(&L[t][o4]) = hv;
  }
  __syncthreads();
#pragma unroll
  for (int p = 0; p < 2; ++p) {
    int idx = p * 256 + tid;          // 512 u16x8 chunks: 32 o x 16
    int o = idx >> 4, t8 = (idx & 15) * 8;
    u16x8 v;
#pragma unroll
    for (int u = 0; u < 8; ++u) v[u] = L[t8 + u][o];
    *(u16x8*)(x1T + (size_t)j * 32768 + (size_t)(oc0 + o) * TT + t8) = v;
  }
}

// ------- K_FINAL2: fused reduce2 + final GEMM (no redundant partH reads) ----
// grid = 32 row-blocks; each block: (a) reduce its 64 rows of partH (8 groups)
// into a swizzled LDS Z-tile, (b) stage its x1h rows, (c) out = Z@Wrel2 +
// x1h@Wroot2 + b2. Same accumulation order as the split version.
__global__ __launch_bounds__(256, 1)
void k_final2(const ushort_t* __restrict__ partH, const ushort_t* __restrict__ x1h,
              const ushort_t* __restrict__ Wrel2T, const ushort_t* __restrict__ Wroot2T,
              const float* __restrict__ b2, float* __restrict__ out) {
  __shared__ ushort_t zbuf[32768];   // 32 KB: 64 rows x 512B (swizzled)
  __shared__ ushort_t xbuf[32768];   // 32 KB
  int bid = blockIdx.x, tid = threadIdx.x;
  int wave = tid >> 6, lane = tid & 63;
  int lr = lane & 15, kg = lane >> 4;
  const size_t Q = (size_t)NODES * TT * HD;
  int R0 = bid * 64;
  // (a) reduce partH groups for rows R0..R0+63 -> zbuf (bf16, swizzled)
#pragma unroll
  for (int p = 0; p < 16; ++p) {
    int idx = p * 256 + tid;              // 4096 quads: 64 r x 64 col-quads
    int r = idx >> 6, c4 = (idx & 63) * 4;
    size_t goff = (size_t)(R0 + r) * HD + c4;
    float4 s = {0.f, 0.f, 0.f, 0.f};
#pragma unroll
    for (int g = 0; g < 8; ++g) {
      u16x4 pv = *(const u16x4*)(partH + (size_t)g * Q + goff);
      s.x += b2f(pv[0]); s.y += b2f(pv[1]); s.z += b2f(pv[2]); s.w += b2f(pv[3]);
    }
    u16x4 hv; hv[0] = f2b(s.x); hv[1] = f2b(s.y); hv[2] = f2b(s.z); hv[3] = f2b(s.w);
    *(u16x4*)((char*)zbuf + r * 512 + ((c4 * 2) ^ ((r & 7) << 4))) = hv;
  }
  // (b) stage x1h rows R0..R0+63 -> xbuf (swizzled)
#pragma unroll
  for (int p = 0; p < 8; ++p) {
    int idx = p * 256 + tid;              // 2048 x 16B chunks: 64 r x 32
    int r = idx >> 5, cb = (idx & 31) << 4;
    u16x8 v = *(const u16x8*)(x1h + (size_t)(R0 + r) * HD + (cb >> 1));
    *(u16x8*)((char*)xbuf + r * 512 + (cb ^ ((r & 7) << 4))) = v;
  }
  __syncthreads();
  // (c) GEMM: acc = Z@Wrel2 + x1h@Wroot2 (wave covers 64 rows x 64 cols)
  int C0 = wave * 64;
  ACC_INIT(acc)
  for (int src = 0; src < 2; ++src) {
    const ushort_t* Abuf = src ? xbuf : zbuf;
    const ushort_t* BT   = src ? Wroot2T : Wrel2T;
    for (int kk = 0; kk < 8; ++kk) {
      int kb = kk * 32 + kg * 8;          // elem index; byte = kb*2
      bf16x8 a[4], b[4];
#pragma unroll
      for (int m = 0; m < 4; ++m) {
        int row = m * 16 + lr;
        a[m] = *(const bf16x8*)((const char*)Abuf + row * 512 + ((kb * 2) ^ ((row & 7) << 4)));
      }
#pragma unroll
      for (int n = 0; n < 4; ++n)
        b[n] = *(const bf16x8*)(BT + (size_t)(C0 + n * 16 + lr) * HD + kb);
#pragma unroll
      for (int m = 0; m < 4; ++m)
#pragma unroll
        for (int n = 0; n < 4; ++n)
          acc[m][n] = __builtin_amdgcn_mfma_f32_16x16x32_bf16(a[m], b[n], acc[m][n], 0, 0, 0);
    }
  }
#pragma unroll
  for (int m = 0; m < 4; ++m)
#pragma unroll
    for (int n = 0; n < 4; ++n) {
      int col = C0 + n * 16 + lr;
      float bb = b2[col];
#pragma unroll
      for (int r = 0; r < 4; ++r) {
        int row = R0 + m * 16 + kg * 4 + r;
        out[(size_t)row * HD + col] = acc[m][n][r] + bb;
      }
    }
}

extern "C" void kernel_launch(void* const* d_in, const int* in_sizes, int n_in,
                              void* d_out, int out_size, void* d_ws, size_t ws_size,
                              hipStream_t stream) {
  (void)in_sizes; (void)n_in; (void)out_size; (void)ws_size;
  const float* G      = (const float*)d_in[0];
  const float* Lf     = (const float*)d_in[1];
  const int*   spk    = (const int*)d_in[2];
  const int*   len    = (const int*)d_in[3];
  const float* Wq     = (const float*)d_in[4];
  const float* Wk     = (const float*)d_in[5];
  const float* vatt   = (const float*)d_in[6];
  const float* Wb1    = (const float*)d_in[7];
  const float* Wb2    = (const float*)d_in[8];
  const float* Wrel1  = (const float*)d_in[9];
  const float* Wroot1 = (const float*)d_in[10];
  const float* b1     = (const float*)d_in[11];
  const float* Wrel2  = (const float*)d_in[12];
  const float* Wroot2 = (const float*)d_in[13];
  const float* b2     = (const float*)d_in[14];

  char* ws = (char*)d_ws;
  const size_t MB = 1ull << 20;
  float*    gw      = (float*)(ws);
  float*    qk      = (float*)(ws + 16 * 1024);
  ushort_t* Lfh     = (ushort_t*)(ws + 1 * MB);
  ushort_t* Wb1T    = (ushort_t*)(ws + 2 * MB);
  ushort_t* Wb2T    = (ushort_t*)(ws + 2 * MB + 64 * 1024);
  ushort_t* Wroot1T = (ushort_t*)(ws + 2 * MB + 128 * 1024);
  ushort_t* Wroot2T = (ushort_t*)(ws + 2 * MB + 256 * 1024);
  ushort_t* Wrel2T  = (ushort_t*)(ws + 2 * MB + 384 * 1024);
  ushort_t* Wrel1T8 = (ushort_t*)(ws + 2 * MB + 512 * 1024);  // 1 MB
  ushort_t* p1h     = (ushort_t*)(ws + 4 * MB);
  ushort_t* p2h     = (ushort_t*)(ws + 4 * MB + 512 * 1024);
  ushort_t* lwT     = (ushort_t*)(ws + 5 * MB);    // 8 MB
  ushort_t* YT      = (ushort_t*)(ws + 21 * MB);   // 4 MB
  float*    x1part  = (float*)(ws + 25 * MB);      // 2 MB
  ushort_t* partH   = (ushort_t*)(ws + 27 * MB);   // 8 MB (8 groups, bf16)
  ushort_t* x1h     = (ushort_t*)(ws + 43 * MB);   // 1 MB
  ushort_t* x1T     = (ushort_t*)(ws + 44 * MB);   // 1 MB
  float* out = (float*)d_out;

  // 1) prep: cast + weight transposes + global-att projections
  k_prep<<<464, 256, 0, stream>>>(Lf, Lfh, Wb1, Wb2, Wroot1, Wroot2, Wrel2, Wrel1,
                                  Wb1T, Wb2T, Wroot1T, Wroot2T, Wrel2T, Wrel1T8,
                                  G, Wq, Wk, qk);
  // 2) phase B: score softmax + p1/p2 + x1root + Y (all independent, dbuf)
  k_phaseB<<<208, 256, 0, stream>>>(qk, vatt, gw, Lfh, Wb1T, Wb2T, p1h, p2h,
                                    Wroot1T, b1, x1part, Wrel1T8, spk, YT);
  // 3) per-edge local attention (dbuf, 2 blocks/CU)
  k_locatt<<<256, 256, 0, stream>>>(p1h, p2h, len, lwT);
  // 4-5) layer-1 aggregation + reduce (bf16 partials)
  k_wagg<<<dim3(8, 16, 2), 256, 0, stream>>>(lwT, YT, gw, spk, partH, 1);
  k_reduce1<<<dim3(16, 8), 256, 0, stream>>>(partH, x1part, x1h, x1T);
  // 6) layer-2 aggregation (bf16 partials)
  k_wagg<<<dim3(8, 16, 2), 256, 0, stream>>>(lwT, x1T, gw, spk, partH, 2);
  // 7) fused reduce2 + final output GEMM
  k_final2<<<32, 256, 0, stream>>>(partH, x1h, Wrel2T, Wroot2T, b2, out);
}

// Round 14
// 74.966 us; speedup vs baseline: 3.2043x; 1.0109x over previous
//
#include <hip/hip_runtime.h>

#define NODES 16
#define TT    128   // tokens per utterance
#define DIM   256   // local feature dim
#define ATTD  128   // attention inner dim
#define HD    256   // hidden dim
#define NEGV  -1e9f

typedef short bf16x8 __attribute__((ext_vector_type(8)));
typedef float f32x4  __attribute__((ext_vector_type(4)));
typedef unsigned short ushort_t;
typedef ushort_t u16x4 __attribute__((ext_vector_type(4)));
typedef ushort_t u16x8 __attribute__((ext_vector_type(8)));

__device__ __forceinline__ ushort_t f2b(float f) {
  union { float f; unsigned u; } v; v.f = f;
  unsigned r = (v.u + 0x7fffu + ((v.u >> 16) & 1u)) >> 16;
  return (ushort_t)r;
}
__device__ __forceinline__ float b2f(ushort_t h) {
  union { unsigned u; float f; } v; v.u = ((unsigned)h) << 16; return v.f;
}

#define WAVE_SETUP                                    \
  int tid = threadIdx.x;                              \
  int wave = tid >> 6, lane = tid & 63;               \
  int wr = wave >> 1, wc = wave & 1;                  \
  int lr = lane & 15, kg = lane >> 4;                 \
  (void)wr; (void)wc;

#define ACC_INIT(acc)                                 \
  f32x4 acc[4][4];                                    \
  { f32x4 z = {0.f, 0.f, 0.f, 0.f};                   \
    _Pragma("unroll") for (int m = 0; m < 4; ++m)     \
    _Pragma("unroll") for (int n = 0; n < 4; ++n) acc[m][n] = z; }

// ---- K-chunk LDS helpers: 128 rows x 64 bf16 (16 KB), 128B rows, swizzle ---
__device__ __forceinline__ void stage_half(const ushort_t* __restrict__ src, int srcs,
                                           ushort_t* __restrict__ dst, int tid) {
#pragma unroll
  for (int p = 0; p < 4; ++p) {
    int idx = p * 256 + tid;               // 1024 x 16B chunks
    int row = idx >> 3;                    // 8 chunks per row
    int cb  = (idx & 7) << 4;              // byte col within 128B row
    u16x8 v = *(const u16x8*)(src + (size_t)row * srcs + (cb >> 1));
    *(u16x8*)((char*)dst + row * 128 + (cb ^ ((row & 7) << 4))) = v;
  }
}

__device__ __forceinline__ void gemm_half(const ushort_t* __restrict__ bufA,
                                          const ushort_t* __restrict__ bufB,
                                          int R0, int C0, int lr, int kg,
                                          f32x4 acc[4][4]) {
#pragma unroll
  for (int kk = 0; kk < 2; ++kk) {
    int cb = kk * 64 + kg * 16;
    bf16x8 a[4], b[4];
#pragma unroll
    for (int m = 0; m < 4; ++m) {
      int row = R0 + m * 16 + lr;
      a[m] = *(const bf16x8*)((const char*)bufA + row * 128 + (cb ^ ((row & 7) << 4)));
    }
#pragma unroll
    for (int n = 0; n < 4; ++n) {
      int row = C0 + n * 16 + lr;
      b[n] = *(const bf16x8*)((const char*)bufB + row * 128 + (cb ^ ((row & 7) << 4)));
    }
#pragma unroll
    for (int m = 0; m < 4; ++m)
#pragma unroll
      for (int n = 0; n < 4; ++n)
        acc[m][n] = __builtin_amdgcn_mfma_f32_16x16x32_bf16(a[m], b[n], acc[m][n], 0, 0, 0);
  }
}

// ============ K_PREP: cast Lf (256) + transpose weights (192) + qk (16) =====
__global__ void k_prep(const float* __restrict__ Lf, ushort_t* __restrict__ Lfh,
                       const float* __restrict__ Wb1, const float* __restrict__ Wb2,
                       const float* __restrict__ Wroot1, const float* __restrict__ Wroot2,
                       const float* __restrict__ Wrel2, const float* __restrict__ Wrel1,
                       ushort_t* __restrict__ Wb1T, ushort_t* __restrict__ Wb2T,
                       ushort_t* __restrict__ Wroot1T, ushort_t* __restrict__ Wroot2T,
                       ushort_t* __restrict__ Wrel2T, ushort_t* __restrict__ Wrel1T8,
                       const float* __restrict__ G, const float* __restrict__ Wq,
                       const float* __restrict__ Wk, float* __restrict__ qk) {
  int blk = blockIdx.x;
  if (blk < 256) {                       // ---- cast local_features to bf16
    int gi = blk * 256 + threadIdx.x;
    const float4* src = (const float4*)Lf;
    float4 v0 = src[gi * 2], v1 = src[gi * 2 + 1];
    u16x8 o;
    o[0] = f2b(v0.x); o[1] = f2b(v0.y); o[2] = f2b(v0.z); o[3] = f2b(v0.w);
    o[4] = f2b(v1.x); o[5] = f2b(v1.y); o[6] = f2b(v1.z); o[7] = f2b(v1.w);
    *(u16x8*)(Lfh + (size_t)gi * 8) = o;
  } else if (blk < 448) {                // ---- cast+transpose weights
    __shared__ float lds[64][65];
    int b = blk - 256;
    const float* src; ushort_t* dst; int C, t;
    if (b < 8)       { src = Wb1;    dst = Wb1T;    C = 128; t = b; }
    else if (b < 16) { src = Wb2;    dst = Wb2T;    C = 128; t = b - 8; }
    else if (b < 32) { src = Wroot1; dst = Wroot1T; C = 256; t = b - 16; }
    else if (b < 48) { src = Wroot2; dst = Wroot2T; C = 256; t = b - 32; }
    else if (b < 64) { src = Wrel2;  dst = Wrel2T;  C = 256; t = b - 48; }
    else {
      int m = (b - 64) >> 4;                 // 0..7 -> spk_i*4 + q
      int relid = (m >> 2) * 32 + (m & 3);   // (spk_i*16 + spk_j)*2 + dir
      src = Wrel1 + (size_t)relid * 65536;
      dst = Wrel1T8 + (size_t)m * 65536;
      C = 256; t = (b - 64) & 15;
    }
    int tilesC = C >> 6;
    int r0 = (t / tilesC) * 64, c0 = (t % tilesC) * 64;
    int tid = threadIdx.x;
    for (int p = 0; p < 16; ++p) {
      int idx = p * 256 + tid, rr = idx >> 6, cc = idx & 63;
      lds[rr][cc] = src[(size_t)(r0 + rr) * C + c0 + cc];
    }
    __syncthreads();
    for (int p = 0; p < 16; ++p) {
      int idx = p * 256 + tid, rr = idx >> 6, cc = idx & 63;
      dst[(size_t)(c0 + rr) * 256 + r0 + cc] = f2b(lds[cc][rr]);
    }
  } else {                               // ---- q/k projections for global att
    int i = blk - 448, t = threadIdx.x;
    const float* W = (t < 128) ? Wq : Wk;
    int a = t & 127;
    float acc = 0.f;
#pragma unroll 8
    for (int d = 0; d < DIM; ++d)
      acc = fmaf(G[i * DIM + d], W[d * ATTD + a], acc);
    int dst = (t < 128) ? i : (NODES + i);
    qk[(size_t)dst * ATTD + a] = acc;
  }
}

// ===== K_PHASEB: score (16) + proj (32) + x1root (32) + y (128) = 208 =======
// GEMM branches: K=256 as 4 chunks, 64 KB dbuf -> 2 blocks/CU
__global__ __launch_bounds__(256, 1)
void k_phaseB(const float* __restrict__ qk, const float* __restrict__ vatt,
              float* __restrict__ gw,
              const ushort_t* __restrict__ Lfh,
              const ushort_t* __restrict__ Wb1T, const ushort_t* __restrict__ Wb2T,
              ushort_t* __restrict__ p1h, ushort_t* __restrict__ p2h,
              const ushort_t* __restrict__ Wroot1T, const float* __restrict__ b1,
              float* __restrict__ x1part,
              const ushort_t* __restrict__ Wrel1T8, const int* __restrict__ spk,
              ushort_t* __restrict__ YT) {
  __shared__ union {
    ushort_t buf[2][16384];                         // 64 KB dbuf (A | B at +8192)
    struct { float sred[NODES][17]; float q[ATTD]; } sc;
  } sh;
  int blk = blockIdx.x;
  if (blk < 16) {                        // ---- global attention scores+softmax
    int i = blk, t = threadIdx.x;
    int j = t >> 4, ag = t & 15;
    if (t < ATTD) sh.sc.q[t] = qk[(size_t)i * ATTD + t];
    __syncthreads();
    float sum = 0.f;
#pragma unroll
    for (int u = 0; u < 8; ++u) {
      int a = ag * 8 + u;
      sum += tanhf(sh.sc.q[a] + qk[(size_t)(NODES + j) * ATTD + a]) * vatt[a];
    }
    sh.sc.sred[j][ag] = sum;
    __syncthreads();
    if (t < NODES) {
      float s = 0.f;
#pragma unroll
      for (int u = 0; u < 16; ++u) s += sh.sc.sred[t][u];
      sh.sc.sred[t][16] = s;
    }
    __syncthreads();
    if (t == 0) {
      float m = -1e30f;
      for (int jj = 0; jj < NODES; ++jj) m = fmaxf(m, sh.sc.sred[jj][16]);
      float ex[NODES], ssum = 0.f;
      for (int jj = 0; jj < NODES; ++jj) { ex[jj] = __expf(sh.sc.sred[jj][16] - m); ssum += ex[jj]; }
      float inv = 1.f / ssum;
      for (int jj = 0; jj < NODES; ++jj) gw[i * NODES + jj] = ex[jj] * inv;
    }
    return;
  }
  // ---- common K=256 dbuf GEMM for the three matmul branches ----
  WAVE_SETUP
  const ushort_t* Asrc; const ushort_t* Bsrc;
  if (blk < 48) {
    int t = blk - 16; int sel = t >> 4, bx = t & 15;
    Asrc = Lfh + (size_t)bx * 128 * DIM;
    Bsrc = sel ? Wb2T : Wb1T;
  } else if (blk < 80) {
    int t = blk - 48; int bx = t & 15, by = t >> 4;
    Asrc = Lfh + (size_t)bx * 128 * DIM;
    Bsrc = Wroot1T + (size_t)by * 128 * DIM;
  } else {
    int t = blk - 80; int iq = t >> 1, cy = t & 1;
    int i = iq >> 2, q = iq & 3;
    int m8 = spk[i] * 4 + q;
    Asrc = Lfh + (size_t)i * TT * DIM;
    Bsrc = Wrel1T8 + (size_t)m8 * 65536 + (size_t)cy * 128 * DIM;
  }
  stage_half(Asrc, DIM, sh.buf[0], tid);
  stage_half(Bsrc, DIM, sh.buf[0] + 8192, tid);
  __syncthreads();
  ACC_INIT(acc)
  for (int c = 1; c < 4; ++c) {
    stage_half(Asrc + c * 64, DIM, sh.buf[c & 1], tid);
    stage_half(Bsrc + c * 64, DIM, sh.buf[c & 1] + 8192, tid);
    gemm_half(sh.buf[(c & 1) ^ 1], sh.buf[(c & 1) ^ 1] + 8192, wr * 64, wc * 64, lr, kg, acc);
    __syncthreads();
  }
  gemm_half(sh.buf[1], sh.buf[1] + 8192, wr * 64, wc * 64, lr, kg, acc);
  // ---- branch-specific epilogue ----
  if (blk < 48) {
    int t = blk - 16; int sel = t >> 4, bx = t & 15;
    ushort_t* out = sel ? p2h : p1h;
    int R0 = bx * 128 + wr * 64, C0 = wc * 64;
#pragma unroll
    for (int m = 0; m < 4; ++m)
#pragma unroll
      for (int n = 0; n < 4; ++n) {
        int col = C0 + n * 16 + lr;
#pragma unroll
        for (int r = 0; r < 4; ++r) {
          int row = R0 + m * 16 + kg * 4 + r;
          out[(size_t)row * ATTD + col] = f2b(acc[m][n][r]);
        }
      }
  } else if (blk < 80) {
    int t = blk - 48; int bx = t & 15, by = t >> 4;
    int R0 = bx * 128 + wr * 64, C0 = by * 128 + wc * 64;
#pragma unroll
    for (int m = 0; m < 4; ++m)
#pragma unroll
      for (int n = 0; n < 4; ++n) {
        int col = C0 + n * 16 + lr;
        float bb = b1[col];
#pragma unroll
        for (int r = 0; r < 4; ++r) {
          int row = R0 + m * 16 + kg * 4 + r;
          x1part[(size_t)row * HD + col] = acc[m][n][r] + bb;
        }
      }
  } else {
    int t = blk - 80; int iq = t >> 1, cy = t & 1;
    int R0 = wr * 64, C0 = cy * 128 + wc * 64;
#pragma unroll
    for (int m = 0; m < 4; ++m)
#pragma unroll
      for (int n = 0; n < 4; ++n) {
        int o = C0 + n * 16 + lr;
        int t0 = R0 + m * 16 + kg * 4;
        u16x4 v;
#pragma unroll
        for (int r = 0; r < 4; ++r) v[r] = f2b(acc[m][n][r]);
        *(u16x4*)(YT + (size_t)iq * 32768 + (size_t)o * TT + t0) = v;
      }
  }
}

// ---------------- per-edge local attention -> lwT (bf16) --------------------
// grid = 256 blocks; K=128 as 2 chunks, S unions stage buf -> 2 blocks/CU
__global__ __launch_bounds__(256, 1)
void k_locatt(const ushort_t* __restrict__ p1h, const ushort_t* __restrict__ p2h,
              const int* __restrict__ length,
              ushort_t* __restrict__ lwT) {
  __shared__ union {
    ushort_t buf[2][16384];   // 64 KB dbuf
    float S[TT][129];         // ~66 KB score matrix (reused after gemm)
  } sh;
  __shared__ float red[TT][2];
  __shared__ float sInv[TT];
  int e = blockIdx.x, i = e >> 4, j = e & 15;
  WAVE_SETUP
  int R0 = wr * 64, C0 = wc * 64;
  const ushort_t* A = p1h + (size_t)i * TT * ATTD;
  const ushort_t* B = p2h + (size_t)j * TT * ATTD;
  stage_half(A, ATTD, sh.buf[0], tid);
  stage_half(B, ATTD, sh.buf[0] + 8192, tid);
  __syncthreads();
  stage_half(A + 64, ATTD, sh.buf[1], tid);
  stage_half(B + 64, ATTD, sh.buf[1] + 8192, tid);
  ACC_INIT(acc)
  gemm_half(sh.buf[0], sh.buf[0] + 8192, R0, C0, lr, kg, acc);
  __syncthreads();
  gemm_half(sh.buf[1], sh.buf[1] + 8192, R0, C0, lr, kg, acc);
  __syncthreads();           // all waves done reading buf before S overwrites
#pragma unroll
  for (int m = 0; m < 4; ++m)
#pragma unroll
    for (int n = 0; n < 4; ++n)
#pragma unroll
      for (int r = 0; r < 4; ++r)
        sh.S[R0 + m * 16 + kg * 4 + r][C0 + n * 16 + lr] = acc[m][n][r];
  __syncthreads();
  int leni = length[i], lenj = length[j];
  int t = tid & 127, h = tid >> 7, s0 = h * 64;
  float mx = -1e30f;
  for (int s = s0; s < s0 + 64; ++s) {
    float vv = (s < lenj) ? sh.S[t][s] : NEGV;
    mx = fmaxf(mx, vv);
  }
  red[t][h] = mx;
  __syncthreads();
  mx = fmaxf(red[t][0], red[t][1]);
  __syncthreads();
  float sum = 0.f;
  for (int s = s0; s < s0 + 64; ++s) {
    float vv = (s < lenj) ? sh.S[t][s] : NEGV;
    float ee = __expf(vv - mx);
    sh.S[t][s] = ee;
    sum += ee;
  }
  red[t][h] = sum;
  __syncthreads();
  if (h == 0) sInv[t] = (t < leni) ? 1.f / (red[t][0] + red[t][1]) : 0.f;
  __syncthreads();
  // transposed write: lwT[e][s][t]
  int s = tid >> 1;
  int t0 = (tid & 1) * 64;
  size_t base = (size_t)e * 16384 + (size_t)s * TT;
  for (int tb = 0; tb < 64; tb += 8) {
    u16x8 w;
#pragma unroll
    for (int u = 0; u < 8; ++u) {
      int tt = t0 + tb + u;
      w[u] = f2b(sh.S[tt][s] * sInv[tt]);
    }
    *(u16x8*)(lwT + base + t0 + tb) = w;
  }
}

// ---------------- weighted aggregation (dbuf K-chunk transpose-GEMM) --------
// partH[g][j][s][o] = bf16( sum_{i in group g} ge_i * (lwT[e]^T-contract) )
// grid = (2 oh, 16 j, 8 g): oh fastest so lwT-sharing pairs are adjacent
// in dispatch order -> same XCD L2. 64 KB LDS -> 2 blocks/CU.
__global__ __launch_bounds__(256, 1)
void k_wagg(const ushort_t* __restrict__ lwT, const ushort_t* __restrict__ Bsrc,
            const float* __restrict__ gw, const int* __restrict__ spk,
            ushort_t* __restrict__ partH, int mode) {
  __shared__ ushort_t buf[2][16384];     // 64 KB dbuf (A | B at +8192)
  int oh = blockIdx.x, j = blockIdx.y, g = blockIdx.z;
  WAVE_SETUP
  int R0 = wr * 64, C0 = wc * 64;
  int i0 = g * 2, i1 = g * 2 + 1;
  int e0 = i0 * NODES + j, e1 = i1 * NODES + j;
  const ushort_t* B0;
  const ushort_t* B1;
  float ge0, ge1;
  if (mode == 1) {
    int q0 = spk[j] * 2 + ((i0 < j) ? 0 : 1);
    int q1 = spk[j] * 2 + ((i1 < j) ? 0 : 1);
    B0 = Bsrc + (size_t)(i0 * 4 + q0) * 32768 + (size_t)oh * 16384;
    B1 = Bsrc + (size_t)(i1 * 4 + q1) * 32768 + (size_t)oh * 16384;
    ge0 = gw[e0]; ge1 = gw[e1];
  } else {
    B0 = Bsrc + (size_t)i0 * 32768 + (size_t)oh * 16384;
    B1 = Bsrc + (size_t)i1 * 32768 + (size_t)oh * 16384;
    ge0 = 1.f; ge1 = 1.f;
  }
  const ushort_t* A0 = lwT + (size_t)e0 * 16384;
  const ushort_t* A1 = lwT + (size_t)e1 * 16384;
  stage_half(A0, TT, buf[0], tid);
  stage_half(B0, TT, buf[0] + 8192, tid);
  __syncthreads();
  stage_half(A0 + 64, TT, buf[1], tid);
  stage_half(B0 + 64, TT, buf[1] + 8192, tid);
  ACC_INIT(acc0)
  gemm_half(buf[0], buf[0] + 8192, R0, C0, lr, kg, acc0);
  __syncthreads();
  stage_half(A1, TT, buf[0], tid);
  stage_half(B1, TT, buf[0] + 8192, tid);
  gemm_half(buf[1], buf[1] + 8192, R0, C0, lr, kg, acc0);
  __syncthreads();
  stage_half(A1 + 64, TT, buf[1], tid);
  stage_half(B1 + 64, TT, buf[1] + 8192, tid);
  ACC_INIT(acc1)
  gemm_half(buf[0], buf[0] + 8192, R0, C0, lr, kg, acc1);
  __syncthreads();
  gemm_half(buf[1], buf[1] + 8192, R0, C0, lr, kg, acc1);
  size_t base = (size_t)(g * NODES + j) * TT * HD + (size_t)oh * 128;
#pragma unroll
  for (int m = 0; m < 4; ++m)
#pragma unroll
    for (int n = 0; n < 4; ++n) {
      int ocol = C0 + n * 16 + lr;
#pragma unroll
      for (int r = 0; r < 4; ++r) {
        int s = R0 + m * 16 + kg * 4 + r;
        partH[base + (size_t)s * HD + ocol] = f2b(ge0 * acc0[m][n][r] + ge1 * acc1[m][n][r]);
      }
    }
}

// ---------------- reduce layer-1 partials -> x1h (bf16) + x1T (bf16) --------
// grid = (16, 8): (node j, 32-col o-block); sums 8 bf16 groups + f32 root term
__global__ __launch_bounds__(256, 1)
void k_reduce1(const ushort_t* __restrict__ partH, const float* __restrict__ x1part,
               ushort_t* __restrict__ x1h, ushort_t* __restrict__ x1T) {
  __shared__ ushort_t L[TT][40];   // [t][o], padded
  int j = blockIdx.x, oc0 = blockIdx.y * 32, tid = threadIdx.x;
  const size_t Q = (size_t)NODES * TT * HD;  // 524288 per group
#pragma unroll
  for (int p = 0; p < 4; ++p) {
    int idx = p * 256 + tid;          // 1024 quads: 128 t x 8
    int t = idx >> 3, o4 = (idx & 7) * 4;
    size_t goff = ((size_t)j * TT + t) * HD + oc0 + o4;
    float4 s = *(const float4*)(x1part + goff);
#pragma unroll
    for (int g = 0; g < 8; ++g) {
      u16x4 pv = *(const u16x4*)(partH + (size_t)g * Q + goff);
      s.x += b2f(pv[0]); s.y += b2f(pv[1]); s.z += b2f(pv[2]); s.w += b2f(pv[3]);
    }
    u16x4 hv; hv[0] = f2b(s.x); hv[1] = f2b(s.y); hv[2] = f2b(s.z); hv[3] = f2b(s.w);
    *(u16x4*)(x1h + goff) = hv;
    *(u16x4*)(&L[t][o4]) = hv;
  }
  __syncthreads();
#pragma unroll
  for (int p = 0; p < 2; ++p) {
    int idx = p * 256 + tid;          // 512 u16x8 chunks: 32 o x 16
    int o = idx >> 4, t8 = (idx & 15) * 8;
    u16x8 v;
#pragma unroll
    for (int u = 0; u < 8; ++u) v[u] = L[t8 + u][o];
    *(u16x8*)(x1T + (size_t)j * 32768 + (size_t)(oc0 + o) * TT + t8) = v;
  }
}

// ---------------- reduce layer-2 partials -> Z2h (bf16, row-major) ----------
__global__ void k_reduce2(const ushort_t* __restrict__ partH, ushort_t* __restrict__ Z2h) {
  int idx = blockIdx.x * 256 + threadIdx.x;  // 131072 quads
  size_t o4 = (size_t)idx * 4;
  const size_t Q = (size_t)NODES * TT * HD;
  float4 s = {0.f, 0.f, 0.f, 0.f};
#pragma unroll
  for (int g = 0; g < 8; ++g) {
    u16x4 pv = *(const u16x4*)(partH + (size_t)g * Q + o4);
    s.x += b2f(pv[0]); s.y += b2f(pv[1]); s.z += b2f(pv[2]); s.w += b2f(pv[3]);
  }
  u16x4 hv; hv[0] = f2b(s.x); hv[1] = f2b(s.y); hv[2] = f2b(s.z); hv[3] = f2b(s.w);
  *(u16x4*)(Z2h + o4) = hv;
}

// ---------------- out = Z2h @ Wrel2 + x1h @ Wroot2 + b2 (f32) ---------------
// grid = (32, 8), 64 threads: one wave per 64x32 tile (256 CUs busy)
__global__ __launch_bounds__(64, 1)
void k_final(const ushort_t* __restrict__ Z2h, const ushort_t* __restrict__ Wrel2T,
             const ushort_t* __restrict__ x1h, const ushort_t* __restrict__ Wroot2T,
             const float* __restrict__ b2, float* __restrict__ out) {
  int lane = threadIdx.x;
  int lr = lane & 15, kg = lane >> 4;
  int R0 = blockIdx.x * 64, C0 = blockIdx.y * 32;
  f32x4 acc[4][2];
  { f32x4 z = {0.f, 0.f, 0.f, 0.f};
#pragma unroll
    for (int m = 0; m < 4; ++m)
#pragma unroll
      for (int n = 0; n < 2; ++n) acc[m][n] = z; }
  for (int src = 0; src < 2; ++src) {
    const ushort_t* A  = src ? x1h : Z2h;
    const ushort_t* BT = src ? Wroot2T : Wrel2T;
    for (int kk = 0; kk < 8; ++kk) {
      int kb = kk * 32 + kg * 8;
      bf16x8 a[4], b[2];
#pragma unroll
      for (int m = 0; m < 4; ++m)
        a[m] = *(const bf16x8*)(A + (size_t)(R0 + m * 16 + lr) * HD + kb);
#pragma unroll
      for (int n = 0; n < 2; ++n)
        b[n] = *(const bf16x8*)(BT + (size_t)(C0 + n * 16 + lr) * HD + kb);
#pragma unroll
      for (int m = 0; m < 4; ++m)
#pragma unroll
        for (int n = 0; n < 2; ++n)
          acc[m][n] = __builtin_amdgcn_mfma_f32_16x16x32_bf16(a[m], b[n], acc[m][n], 0, 0, 0);
    }
  }
#pragma unroll
  for (int m = 0; m < 4; ++m)
#pragma unroll
    for (int n = 0; n < 2; ++n) {
      int col = C0 + n * 16 + lr;
      float bb = b2[col];
#pragma unroll
      for (int r = 0; r < 4; ++r) {
        int row = R0 + m * 16 + kg * 4 + r;
        out[(size_t)row * HD + col] = acc[m][n][r] + bb;
      }
    }
}

extern "C" void kernel_launch(void* const* d_in, const int* in_sizes, int n_in,
                              void* d_out, int out_size, void* d_ws, size_t ws_size,
                              hipStream_t stream) {
  (void)in_sizes; (void)n_in; (void)out_size; (void)ws_size;
  const float* G      = (const float*)d_in[0];
  const float* Lf     = (const float*)d_in[1];
  const int*   spk    = (const int*)d_in[2];
  const int*   len    = (const int*)d_in[3];
  const float* Wq     = (const float*)d_in[4];
  const float* Wk     = (const float*)d_in[5];
  const float* vatt   = (const float*)d_in[6];
  const float* Wb1    = (const float*)d_in[7];
  const float* Wb2    = (const float*)d_in[8];
  const float* Wrel1  = (const float*)d_in[9];
  const float* Wroot1 = (const float*)d_in[10];
  const float* b1     = (const float*)d_in[11];
  const float* Wrel2  = (const float*)d_in[12];
  const float* Wroot2 = (const float*)d_in[13];
  const float* b2     = (const float*)d_in[14];

  char* ws = (char*)d_ws;
  const size_t MB = 1ull << 20;
  float*    gw      = (float*)(ws);
  float*    qk      = (float*)(ws + 16 * 1024);
  ushort_t* Lfh     = (ushort_t*)(ws + 1 * MB);
  ushort_t* Wb1T    = (ushort_t*)(ws + 2 * MB);
  ushort_t* Wb2T    = (ushort_t*)(ws + 2 * MB + 64 * 1024);
  ushort_t* Wroot1T = (ushort_t*)(ws + 2 * MB + 128 * 1024);
  ushort_t* Wroot2T = (ushort_t*)(ws + 2 * MB + 256 * 1024);
  ushort_t* Wrel2T  = (ushort_t*)(ws + 2 * MB + 384 * 1024);
  ushort_t* Wrel1T8 = (ushort_t*)(ws + 2 * MB + 512 * 1024);  // 1 MB
  ushort_t* p1h     = (ushort_t*)(ws + 4 * MB);
  ushort_t* p2h     = (ushort_t*)(ws + 4 * MB + 512 * 1024);
  ushort_t* lwT     = (ushort_t*)(ws + 5 * MB);    // 8 MB
  ushort_t* YT      = (ushort_t*)(ws + 21 * MB);   // 4 MB
  float*    x1part  = (float*)(ws + 25 * MB);      // 2 MB
  ushort_t* partH   = (ushort_t*)(ws + 27 * MB);   // 8 MB (8 groups, bf16)
  ushort_t* x1h     = (ushort_t*)(ws + 43 * MB);   // 1 MB
  ushort_t* x1T     = (ushort_t*)(ws + 44 * MB);   // 1 MB
  ushort_t* Z2h     = (ushort_t*)(ws + 45 * MB);   // 1 MB
  float* out = (float*)d_out;

  // 1) prep: cast + weight transposes + global-att projections
  k_prep<<<464, 256, 0, stream>>>(Lf, Lfh, Wb1, Wb2, Wroot1, Wroot2, Wrel2, Wrel1,
                                  Wb1T, Wb2T, Wroot1T, Wroot2T, Wrel2T, Wrel1T8,
                                  G, Wq, Wk, qk);
  // 2) phase B: score softmax + p1/p2 + x1root + Y (all independent, dbuf)
  k_phaseB<<<208, 256, 0, stream>>>(qk, vatt, gw, Lfh, Wb1T, Wb2T, p1h, p2h,
                                    Wroot1T, b1, x1part, Wrel1T8, spk, YT);
  // 3) per-edge local attention (dbuf, 2 blocks/CU)
  k_locatt<<<256, 256, 0, stream>>>(p1h, p2h, len, lwT);
  // 4-5) layer-1 aggregation + reduce (bf16 partials; oh-fastest block order)
  k_wagg<<<dim3(2, 16, 8), 256, 0, stream>>>(lwT, YT, gw, spk, partH, 1);
  k_reduce1<<<dim3(16, 8), 256, 0, stream>>>(partH, x1part, x1h, x1T);
  // 6-7) layer-2 aggregation + reduce
  k_wagg<<<dim3(2, 16, 8), 256, 0, stream>>>(lwT, x1T, gw, spk, partH, 2);
  k_reduce2<<<512, 256, 0, stream>>>(partH, Z2h);
  // 8) final fused output GEMM (256 single-wave blocks)
  k_final<<<dim3(32, 8), 64, 0, stream>>>(Z2h, Wrel2T, x1h, Wroot2T, b2, out);
}

// Round 15
// 73.520 us; speedup vs baseline: 3.2673x; 1.0197x over previous
//
#include <hip/hip_runtime.h>

#define NODES 16
#define TT    128   // tokens per utterance
#define DIM   256   // local feature dim
#define ATTD  128   // attention inner dim
#define HD    256   // hidden dim
#define NEGV  -1e9f

typedef short bf16x8 __attribute__((ext_vector_type(8)));
typedef float f32x4  __attribute__((ext_vector_type(4)));
typedef unsigned short ushort_t;
typedef ushort_t u16x4 __attribute__((ext_vector_type(4)));
typedef ushort_t u16x8 __attribute__((ext_vector_type(8)));

__device__ __forceinline__ ushort_t f2b(float f) {
  union { float f; unsigned u; } v; v.f = f;
  unsigned r = (v.u + 0x7fffu + ((v.u >> 16) & 1u)) >> 16;
  return (ushort_t)r;
}
__device__ __forceinline__ float b2f(ushort_t h) {
  union { unsigned u; float f; } v; v.u = ((unsigned)h) << 16; return v.f;
}

#define WAVE_SETUP                                    \
  int tid = threadIdx.x;                              \
  int wave = tid >> 6, lane = tid & 63;               \
  int wr = wave >> 1, wc = wave & 1;                  \
  int lr = lane & 15, kg = lane >> 4;                 \
  (void)wr; (void)wc;

#define ACC_INIT(acc)                                 \
  f32x4 acc[4][4];                                    \
  { f32x4 z = {0.f, 0.f, 0.f, 0.f};                   \
    _Pragma("unroll") for (int m = 0; m < 4; ++m)     \
    _Pragma("unroll") for (int n = 0; n < 4; ++n) acc[m][n] = z; }

// ---- K-chunk LDS helpers: 128 rows x 64 bf16 (16 KB), 128B rows, swizzle ---
__device__ __forceinline__ void stage_half(const ushort_t* __restrict__ src, int srcs,
                                           ushort_t* __restrict__ dst, int tid) {
#pragma unroll
  for (int p = 0; p < 4; ++p) {
    int idx = p * 256 + tid;               // 1024 x 16B chunks
    int row = idx >> 3;                    // 8 chunks per row
    int cb  = (idx & 7) << 4;              // byte col within 128B row
    u16x8 v = *(const u16x8*)(src + (size_t)row * srcs + (cb >> 1));
    *(u16x8*)((char*)dst + row * 128 + (cb ^ ((row & 7) << 4))) = v;
  }
}

__device__ __forceinline__ void gemm_half(const ushort_t* __restrict__ bufA,
                                          const ushort_t* __restrict__ bufB,
                                          int R0, int C0, int lr, int kg,
                                          f32x4 acc[4][4]) {
#pragma unroll
  for (int kk = 0; kk < 2; ++kk) {
    int cb = kk * 64 + kg * 16;
    bf16x8 a[4], b[4];
#pragma unroll
    for (int m = 0; m < 4; ++m) {
      int row = R0 + m * 16 + lr;
      a[m] = *(const bf16x8*)((const char*)bufA + row * 128 + (cb ^ ((row & 7) << 4)));
    }
#pragma unroll
    for (int n = 0; n < 4; ++n) {
      int row = C0 + n * 16 + lr;
      b[n] = *(const bf16x8*)((const char*)bufB + row * 128 + (cb ^ ((row & 7) << 4)));
    }
#pragma unroll
    for (int m = 0; m < 4; ++m)
#pragma unroll
      for (int n = 0; n < 4; ++n)
        acc[m][n] = __builtin_amdgcn_mfma_f32_16x16x32_bf16(a[m], b[n], acc[m][n], 0, 0, 0);
  }
}

// ============ K_PREP: cast Lf (256) + transpose weights (192) + qk (16) =====
__global__ void k_prep(const float* __restrict__ Lf, ushort_t* __restrict__ Lfh,
                       const float* __restrict__ Wb1, const float* __restrict__ Wb2,
                       const float* __restrict__ Wroot1, const float* __restrict__ Wroot2,
                       const float* __restrict__ Wrel2, const float* __restrict__ Wrel1,
                       ushort_t* __restrict__ Wb1T, ushort_t* __restrict__ Wb2T,
                       ushort_t* __restrict__ Wroot1T, ushort_t* __restrict__ Wroot2T,
                       ushort_t* __restrict__ Wrel2T, ushort_t* __restrict__ Wrel1T8,
                       const float* __restrict__ G, const float* __restrict__ Wq,
                       const float* __restrict__ Wk, float* __restrict__ qk) {
  int blk = blockIdx.x;
  if (blk < 256) {                       // ---- cast local_features to bf16
    int gi = blk * 256 + threadIdx.x;
    const float4* src = (const float4*)Lf;
    float4 v0 = src[gi * 2], v1 = src[gi * 2 + 1];
    u16x8 o;
    o[0] = f2b(v0.x); o[1] = f2b(v0.y); o[2] = f2b(v0.z); o[3] = f2b(v0.w);
    o[4] = f2b(v1.x); o[5] = f2b(v1.y); o[6] = f2b(v1.z); o[7] = f2b(v1.w);
    *(u16x8*)(Lfh + (size_t)gi * 8) = o;
  } else if (blk < 448) {                // ---- cast+transpose weights
    __shared__ float lds[64][65];
    int b = blk - 256;
    const float* src; ushort_t* dst; int C, t;
    if (b < 8)       { src = Wb1;    dst = Wb1T;    C = 128; t = b; }
    else if (b < 16) { src = Wb2;    dst = Wb2T;    C = 128; t = b - 8; }
    else if (b < 32) { src = Wroot1; dst = Wroot1T; C = 256; t = b - 16; }
    else if (b < 48) { src = Wroot2; dst = Wroot2T; C = 256; t = b - 32; }
    else if (b < 64) { src = Wrel2;  dst = Wrel2T;  C = 256; t = b - 48; }
    else {
      int m = (b - 64) >> 4;                 // 0..7 -> spk_i*4 + q
      int relid = (m >> 2) * 32 + (m & 3);   // (spk_i*16 + spk_j)*2 + dir
      src = Wrel1 + (size_t)relid * 65536;
      dst = Wrel1T8 + (size_t)m * 65536;
      C = 256; t = (b - 64) & 15;
    }
    int tilesC = C >> 6;
    int r0 = (t / tilesC) * 64, c0 = (t % tilesC) * 64;
    int tid = threadIdx.x;
    for (int p = 0; p < 16; ++p) {
      int idx = p * 256 + tid, rr = idx >> 6, cc = idx & 63;
      lds[rr][cc] = src[(size_t)(r0 + rr) * C + c0 + cc];
    }
    __syncthreads();
    for (int p = 0; p < 16; ++p) {
      int idx = p * 256 + tid, rr = idx >> 6, cc = idx & 63;
      dst[(size_t)(c0 + rr) * 256 + r0 + cc] = f2b(lds[cc][rr]);
    }
  } else {                               // ---- q/k projections for global att
    int i = blk - 448, t = threadIdx.x;
    const float* W = (t < 128) ? Wq : Wk;
    int a = t & 127;
    float acc = 0.f;
#pragma unroll 8
    for (int d = 0; d < DIM; ++d)
      acc = fmaf(G[i * DIM + d], W[d * ATTD + a], acc);
    int dst = (t < 128) ? i : (NODES + i);
    qk[(size_t)dst * ATTD + a] = acc;
  }
}

// ===== K_PHASEB: score (16) + proj (32) + x1root (32) + y (128) = 208 =======
// GEMM branches: K=256 as 4 chunks, 64 KB dbuf -> 2 blocks/CU
__global__ __launch_bounds__(256, 1)
void k_phaseB(const float* __restrict__ qk, const float* __restrict__ vatt,
              float* __restrict__ gw,
              const ushort_t* __restrict__ Lfh,
              const ushort_t* __restrict__ Wb1T, const ushort_t* __restrict__ Wb2T,
              ushort_t* __restrict__ p1h, ushort_t* __restrict__ p2h,
              const ushort_t* __restrict__ Wroot1T, const float* __restrict__ b1,
              float* __restrict__ x1part,
              const ushort_t* __restrict__ Wrel1T8, const int* __restrict__ spk,
              ushort_t* __restrict__ YT) {
  __shared__ union {
    ushort_t buf[2][16384];                         // 64 KB dbuf (A | B at +8192)
    struct { float sred[NODES][17]; float q[ATTD]; } sc;
  } sh;
  int blk = blockIdx.x;
  if (blk < 16) {                        // ---- global attention scores+softmax
    int i = blk, t = threadIdx.x;
    int j = t >> 4, ag = t & 15;
    if (t < ATTD) sh.sc.q[t] = qk[(size_t)i * ATTD + t];
    __syncthreads();
    float sum = 0.f;
#pragma unroll
    for (int u = 0; u < 8; ++u) {
      int a = ag * 8 + u;
      sum += tanhf(sh.sc.q[a] + qk[(size_t)(NODES + j) * ATTD + a]) * vatt[a];
    }
    sh.sc.sred[j][ag] = sum;
    __syncthreads();
    if (t < NODES) {
      float s = 0.f;
#pragma unroll
      for (int u = 0; u < 16; ++u) s += sh.sc.sred[t][u];
      sh.sc.sred[t][16] = s;
    }
    __syncthreads();
    if (t == 0) {
      float m = -1e30f;
      for (int jj = 0; jj < NODES; ++jj) m = fmaxf(m, sh.sc.sred[jj][16]);
      float ex[NODES], ssum = 0.f;
      for (int jj = 0; jj < NODES; ++jj) { ex[jj] = __expf(sh.sc.sred[jj][16] - m); ssum += ex[jj]; }
      float inv = 1.f / ssum;
      for (int jj = 0; jj < NODES; ++jj) gw[i * NODES + jj] = ex[jj] * inv;
    }
    return;
  }
  // ---- common K=256 dbuf GEMM for the three matmul branches ----
  WAVE_SETUP
  const ushort_t* Asrc; const ushort_t* Bsrc;
  if (blk < 48) {
    int t = blk - 16; int sel = t >> 4, bx = t & 15;
    Asrc = Lfh + (size_t)bx * 128 * DIM;
    Bsrc = sel ? Wb2T : Wb1T;
  } else if (blk < 80) {
    int t = blk - 48; int bx = t & 15, by = t >> 4;
    Asrc = Lfh + (size_t)bx * 128 * DIM;
    Bsrc = Wroot1T + (size_t)by * 128 * DIM;
  } else {
    int t = blk - 80; int iq = t >> 1, cy = t & 1;
    int i = iq >> 2, q = iq & 3;
    int m8 = spk[i] * 4 + q;
    Asrc = Lfh + (size_t)i * TT * DIM;
    Bsrc = Wrel1T8 + (size_t)m8 * 65536 + (size_t)cy * 128 * DIM;
  }
  stage_half(Asrc, DIM, sh.buf[0], tid);
  stage_half(Bsrc, DIM, sh.buf[0] + 8192, tid);
  __syncthreads();
  ACC_INIT(acc)
  for (int c = 1; c < 4; ++c) {
    stage_half(Asrc + c * 64, DIM, sh.buf[c & 1], tid);
    stage_half(Bsrc + c * 64, DIM, sh.buf[c & 1] + 8192, tid);
    gemm_half(sh.buf[(c & 1) ^ 1], sh.buf[(c & 1) ^ 1] + 8192, wr * 64, wc * 64, lr, kg, acc);
    __syncthreads();
  }
  gemm_half(sh.buf[1], sh.buf[1] + 8192, wr * 64, wc * 64, lr, kg, acc);
  // ---- branch-specific epilogue ----
  if (blk < 48) {
    int t = blk - 16; int sel = t >> 4, bx = t & 15;
    ushort_t* out = sel ? p2h : p1h;
    int R0 = bx * 128 + wr * 64, C0 = wc * 64;
#pragma unroll
    for (int m = 0; m < 4; ++m)
#pragma unroll
      for (int n = 0; n < 4; ++n) {
        int col = C0 + n * 16 + lr;
#pragma unroll
        for (int r = 0; r < 4; ++r) {
          int row = R0 + m * 16 + kg * 4 + r;
          out[(size_t)row * ATTD + col] = f2b(acc[m][n][r]);
        }
      }
  } else if (blk < 80) {
    int t = blk - 48; int bx = t & 15, by = t >> 4;
    int R0 = bx * 128 + wr * 64, C0 = by * 128 + wc * 64;
#pragma unroll
    for (int m = 0; m < 4; ++m)
#pragma unroll
      for (int n = 0; n < 4; ++n) {
        int col = C0 + n * 16 + lr;
        float bb = b1[col];
#pragma unroll
        for (int r = 0; r < 4; ++r) {
          int row = R0 + m * 16 + kg * 4 + r;
          x1part[(size_t)row * HD + col] = acc[m][n][r] + bb;
        }
      }
  } else {
    int t = blk - 80; int iq = t >> 1, cy = t & 1;
    int R0 = wr * 64, C0 = cy * 128 + wc * 64;
#pragma unroll
    for (int m = 0; m < 4; ++m)
#pragma unroll
      for (int n = 0; n < 4; ++n) {
        int o = C0 + n * 16 + lr;
        int t0 = R0 + m * 16 + kg * 4;
        u16x4 v;
#pragma unroll
        for (int r = 0; r < 4; ++r) v[r] = f2b(acc[m][n][r]);
        *(u16x4*)(YT + (size_t)iq * 32768 + (size_t)o * TT + t0) = v;
      }
  }
}

// ---------------- per-edge local attention -> lwT (bf16) --------------------
// grid = 256 blocks; K=128 as 2 chunks, S unions stage buf -> 2 blocks/CU
__global__ __launch_bounds__(256, 1)
void k_locatt(const ushort_t* __restrict__ p1h, const ushort_t* __restrict__ p2h,
              const int* __restrict__ length,
              ushort_t* __restrict__ lwT) {
  __shared__ union {
    ushort_t buf[2][16384];   // 64 KB dbuf
    float S[TT][129];         // ~66 KB score matrix (reused after gemm)
  } sh;
  __shared__ float red[TT][2];
  __shared__ float sInv[TT];
  int e = blockIdx.x, i = e >> 4, j = e & 15;
  WAVE_SETUP
  int R0 = wr * 64, C0 = wc * 64;
  const ushort_t* A = p1h + (size_t)i * TT * ATTD;
  const ushort_t* B = p2h + (size_t)j * TT * ATTD;
  stage_half(A, ATTD, sh.buf[0], tid);
  stage_half(B, ATTD, sh.buf[0] + 8192, tid);
  __syncthreads();
  stage_half(A + 64, ATTD, sh.buf[1], tid);
  stage_half(B + 64, ATTD, sh.buf[1] + 8192, tid);
  ACC_INIT(acc)
  gemm_half(sh.buf[0], sh.buf[0] + 8192, R0, C0, lr, kg, acc);
  __syncthreads();
  gemm_half(sh.buf[1], sh.buf[1] + 8192, R0, C0, lr, kg, acc);
  __syncthreads();           // all waves done reading buf before S overwrites
#pragma unroll
  for (int m = 0; m < 4; ++m)
#pragma unroll
    for (int n = 0; n < 4; ++n)
#pragma unroll
      for (int r = 0; r < 4; ++r)
        sh.S[R0 + m * 16 + kg * 4 + r][C0 + n * 16 + lr] = acc[m][n][r];
  __syncthreads();
  int leni = length[i], lenj = length[j];
  int t = tid & 127, h = tid >> 7, s0 = h * 64;
  float mx = -1e30f;
  for (int s = s0; s < s0 + 64; ++s) {
    float vv = (s < lenj) ? sh.S[t][s] : NEGV;
    mx = fmaxf(mx, vv);
  }
  red[t][h] = mx;
  __syncthreads();
  mx = fmaxf(red[t][0], red[t][1]);
  __syncthreads();
  float sum = 0.f;
  for (int s = s0; s < s0 + 64; ++s) {
    float vv = (s < lenj) ? sh.S[t][s] : NEGV;
    float ee = __expf(vv - mx);
    sh.S[t][s] = ee;
    sum += ee;
  }
  red[t][h] = sum;
  __syncthreads();
  if (h == 0) sInv[t] = (t < leni) ? 1.f / (red[t][0] + red[t][1]) : 0.f;
  __syncthreads();
  // transposed write: lwT[e][s][t]
  int s = tid >> 1;
  int t0 = (tid & 1) * 64;
  size_t base = (size_t)e * 16384 + (size_t)s * TT;
  for (int tb = 0; tb < 64; tb += 8) {
    u16x8 w;
#pragma unroll
    for (int u = 0; u < 8; ++u) {
      int tt = t0 + tb + u;
      w[u] = f2b(sh.S[tt][s] * sInv[tt]);
    }
    *(u16x8*)(lwT + base + t0 + tb) = w;
  }
}

// ---------------- weighted aggregation (dbuf K-chunk transpose-GEMM) --------
// partH[g][j][s][o] = bf16( sum_{i in group g} ge_i * (lwT[e]^T-contract) )
// grid = (8, 16, 2); 64 KB LDS -> 2 blocks/CU   [best-measured r11 order]
__global__ __launch_bounds__(256, 1)
void k_wagg(const ushort_t* __restrict__ lwT, const ushort_t* __restrict__ Bsrc,
            const float* __restrict__ gw, const int* __restrict__ spk,
            ushort_t* __restrict__ partH, int mode) {
  __shared__ ushort_t buf[2][16384];     // 64 KB dbuf (A | B at +8192)
  int g = blockIdx.x, j = blockIdx.y, oh = blockIdx.z;
  WAVE_SETUP
  int R0 = wr * 64, C0 = wc * 64;
  int i0 = g * 2, i1 = g * 2 + 1;
  int e0 = i0 * NODES + j, e1 = i1 * NODES + j;
  const ushort_t* B0;
  const ushort_t* B1;
  float ge0, ge1;
  if (mode == 1) {
    int q0 = spk[j] * 2 + ((i0 < j) ? 0 : 1);
    int q1 = spk[j] * 2 + ((i1 < j) ? 0 : 1);
    B0 = Bsrc + (size_t)(i0 * 4 + q0) * 32768 + (size_t)oh * 16384;
    B1 = Bsrc + (size_t)(i1 * 4 + q1) * 32768 + (size_t)oh * 16384;
    ge0 = gw[e0]; ge1 = gw[e1];
  } else {
    B0 = Bsrc + (size_t)i0 * 32768 + (size_t)oh * 16384;
    B1 = Bsrc + (size_t)i1 * 32768 + (size_t)oh * 16384;
    ge0 = 1.f; ge1 = 1.f;
  }
  const ushort_t* A0 = lwT + (size_t)e0 * 16384;
  const ushort_t* A1 = lwT + (size_t)e1 * 16384;
  stage_half(A0, TT, buf[0], tid);
  stage_half(B0, TT, buf[0] + 8192, tid);
  __syncthreads();
  stage_half(A0 + 64, TT, buf[1], tid);
  stage_half(B0 + 64, TT, buf[1] + 8192, tid);
  ACC_INIT(acc0)
  gemm_half(buf[0], buf[0] + 8192, R0, C0, lr, kg, acc0);
  __syncthreads();
  stage_half(A1, TT, buf[0], tid);
  stage_half(B1, TT, buf[0] + 8192, tid);
  gemm_half(buf[1], buf[1] + 8192, R0, C0, lr, kg, acc0);
  __syncthreads();
  stage_half(A1 + 64, TT, buf[1], tid);
  stage_half(B1 + 64, TT, buf[1] + 8192, tid);
  ACC_INIT(acc1)
  gemm_half(buf[0], buf[0] + 8192, R0, C0, lr, kg, acc1);
  __syncthreads();
  gemm_half(buf[1], buf[1] + 8192, R0, C0, lr, kg, acc1);
  size_t base = (size_t)(g * NODES + j) * TT * HD + (size_t)oh * 128;
#pragma unroll
  for (int m = 0; m < 4; ++m)
#pragma unroll
    for (int n = 0; n < 4; ++n) {
      int ocol = C0 + n * 16 + lr;
#pragma unroll
      for (int r = 0; r < 4; ++r) {
        int s = R0 + m * 16 + kg * 4 + r;
        partH[base + (size_t)s * HD + ocol] = f2b(ge0 * acc0[m][n][r] + ge1 * acc1[m][n][r]);
      }
    }
}

// ---------------- reduce layer-1 partials -> x1h (bf16) + x1T (bf16) --------
// grid = (16, 8): (node j, 32-col o-block); sums 8 bf16 groups + f32 root term
__global__ __launch_bounds__(256, 1)
void k_reduce1(const ushort_t* __restrict__ partH, const float* __restrict__ x1part,
               ushort_t* __restrict__ x1h, ushort_t* __restrict__ x1T) {
  __shared__ ushort_t L[TT][40];   // [t][o], padded
  int j = blockIdx.x, oc0 = blockIdx.y * 32, tid = threadIdx.x;
  const size_t Q = (size_t)NODES * TT * HD;  // 524288 per group
#pragma unroll
  for (int p = 0; p < 4; ++p) {
    int idx = p * 256 + tid;          // 1024 quads: 128 t x 8
    int t = idx >> 3, o4 = (idx & 7) * 4;
    size_t goff = ((size_t)j * TT + t) * HD + oc0 + o4;
    float4 s = *(const float4*)(x1part + goff);
#pragma unroll
    for (int g = 0; g < 8; ++g) {
      u16x4 pv = *(const u16x4*)(partH + (size_t)g * Q + goff);
      s.x += b2f(pv[0]); s.y += b2f(pv[1]); s.z += b2f(pv[2]); s.w += b2f(pv[3]);
    }
    u16x4 hv; hv[0] = f2b(s.x); hv[1] = f2b(s.y); hv[2] = f2b(s.z); hv[3] = f2b(s.w);
    *(u16x4*)(x1h + goff) = hv;
    *(u16x4*)(&L[t][o4]) = hv;
  }
  __syncthreads();
#pragma unroll
  for (int p = 0; p < 2; ++p) {
    int idx = p * 256 + tid;          // 512 u16x8 chunks: 32 o x 16
    int o = idx >> 4, t8 = (idx & 15) * 8;
    u16x8 v;
#pragma unroll
    for (int u = 0; u < 8; ++u) v[u] = L[t8 + u][o];
    *(u16x8*)(x1T + (size_t)j * 32768 + (size_t)(oc0 + o) * TT + t8) = v;
  }
}

// ---------------- reduce layer-2 partials -> Z2h (bf16, row-major) ----------
__global__ void k_reduce2(const ushort_t* __restrict__ partH, ushort_t* __restrict__ Z2h) {
  int idx = blockIdx.x * 256 + threadIdx.x;  // 131072 quads
  size_t o4 = (size_t)idx * 4;
  const size_t Q = (size_t)NODES * TT * HD;
  float4 s = {0.f, 0.f, 0.f, 0.f};
#pragma unroll
  for (int g = 0; g < 8; ++g) {
    u16x4 pv = *(const u16x4*)(partH + (size_t)g * Q + o4);
    s.x += b2f(pv[0]); s.y += b2f(pv[1]); s.z += b2f(pv[2]); s.w += b2f(pv[3]);
  }
  u16x4 hv; hv[0] = f2b(s.x); hv[1] = f2b(s.y); hv[2] = f2b(s.z); hv[3] = f2b(s.w);
  *(u16x4*)(Z2h + o4) = hv;
}

// ---------------- out = Z2h @ Wrel2 + x1h @ Wroot2 + b2 (f32) ---------------
// grid = (32, 8), 64 threads: one wave per 64x32 tile (256 CUs busy)
__global__ __launch_bounds__(64, 1)
void k_final(const ushort_t* __restrict__ Z2h, const ushort_t* __restrict__ Wrel2T,
             const ushort_t* __restrict__ x1h, const ushort_t* __restrict__ Wroot2T,
             const float* __restrict__ b2, float* __restrict__ out) {
  int lane = threadIdx.x;
  int lr = lane & 15, kg = lane >> 4;
  int R0 = blockIdx.x * 64, C0 = blockIdx.y * 32;
  f32x4 acc[4][2];
  { f32x4 z = {0.f, 0.f, 0.f, 0.f};
#pragma unroll
    for (int m = 0; m < 4; ++m)
#pragma unroll
      for (int n = 0; n < 2; ++n) acc[m][n] = z; }
  for (int src = 0; src < 2; ++src) {
    const ushort_t* A  = src ? x1h : Z2h;
    const ushort_t* BT = src ? Wroot2T : Wrel2T;
    for (int kk = 0; kk < 8; ++kk) {
      int kb = kk * 32 + kg * 8;
      bf16x8 a[4], b[2];
#pragma unroll
      for (int m = 0; m < 4; ++m)
        a[m] = *(const bf16x8*)(A + (size_t)(R0 + m * 16 + lr) * HD + kb);
#pragma unroll
      for (int n = 0; n < 2; ++n)
        b[n] = *(const bf16x8*)(BT + (size_t)(C0 + n * 16 + lr) * HD + kb);
#pragma unroll
      for (int m = 0; m < 4; ++m)
#pragma unroll
        for (int n = 0; n < 2; ++n)
          acc[m][n] = __builtin_amdgcn_mfma_f32_16x16x32_bf16(a[m], b[n], acc[m][n], 0, 0, 0);
    }
  }
#pragma unroll
  for (int m = 0; m < 4; ++m)
#pragma unroll
    for (int n = 0; n < 2; ++n) {
      int col = C0 + n * 16 + lr;
      float bb = b2[col];
#pragma unroll
      for (int r = 0; r < 4; ++r) {
        int row = R0 + m * 16 + kg * 4 + r;
        out[(size_t)row * HD + col] = acc[m][n][r] + bb;
      }
    }
}

extern "C" void kernel_launch(void* const* d_in, const int* in_sizes, int n_in,
                              void* d_out, int out_size, void* d_ws, size_t ws_size,
                              hipStream_t stream) {
  (void)in_sizes; (void)n_in; (void)out_size; (void)ws_size;
  const float* G      = (const float*)d_in[0];
  const float* Lf     = (const float*)d_in[1];
  const int*   spk    = (const int*)d_in[2];
  const int*   len    = (const int*)d_in[3];
  const float* Wq     = (const float*)d_in[4];
  const float* Wk     = (const float*)d_in[5];
  const float* vatt   = (const float*)d_in[6];
  const float* Wb1    = (const float*)d_in[7];
  const float* Wb2    = (const float*)d_in[8];
  const float* Wrel1  = (const float*)d_in[9];
  const float* Wroot1 = (const float*)d_in[10];
  const float* b1     = (const float*)d_in[11];
  const float* Wrel2  = (const float*)d_in[12];
  const float* Wroot2 = (const float*)d_in[13];
  const float* b2     = (const float*)d_in[14];

  char* ws = (char*)d_ws;
  const size_t MB = 1ull << 20;
  float*    gw      = (float*)(ws);
  float*    qk      = (float*)(ws + 16 * 1024);
  ushort_t* Lfh     = (ushort_t*)(ws + 1 * MB);
  ushort_t* Wb1T    = (ushort_t*)(ws + 2 * MB);
  ushort_t* Wb2T    = (ushort_t*)(ws + 2 * MB + 64 * 1024);
  ushort_t* Wroot1T = (ushort_t*)(ws + 2 * MB + 128 * 1024);
  ushort_t* Wroot2T = (ushort_t*)(ws + 2 * MB + 256 * 1024);
  ushort_t* Wrel2T  = (ushort_t*)(ws + 2 * MB + 384 * 1024);
  ushort_t* Wrel1T8 = (ushort_t*)(ws + 2 * MB + 512 * 1024);  // 1 MB
  ushort_t* p1h     = (ushort_t*)(ws + 4 * MB);
  ushort_t* p2h     = (ushort_t*)(ws + 4 * MB + 512 * 1024);
  ushort_t* lwT     = (ushort_t*)(ws + 5 * MB);    // 8 MB
  ushort_t* YT      = (ushort_t*)(ws + 21 * MB);   // 4 MB
  float*    x1part  = (float*)(ws + 25 * MB);      // 2 MB
  ushort_t* partH   = (ushort_t*)(ws + 27 * MB);   // 8 MB (8 groups, bf16)
  ushort_t* x1h     = (ushort_t*)(ws + 43 * MB);   // 1 MB
  ushort_t* x1T     = (ushort_t*)(ws + 44 * MB);   // 1 MB
  ushort_t* Z2h     = (ushort_t*)(ws + 45 * MB);   // 1 MB
  float* out = (float*)d_out;

  // 1) prep: cast + weight transposes + global-att projections
  k_prep<<<464, 256, 0, stream>>>(Lf, Lfh, Wb1, Wb2, Wroot1, Wroot2, Wrel2, Wrel1,
                                  Wb1T, Wb2T, Wroot1T, Wroot2T, Wrel2T, Wrel1T8,
                                  G, Wq, Wk, qk);
  // 2) phase B: score softmax + p1/p2 + x1root + Y (all independent, dbuf)
  k_phaseB<<<208, 256, 0, stream>>>(qk, vatt, gw, Lfh, Wb1T, Wb2T, p1h, p2h,
                                    Wroot1T, b1, x1part, Wrel1T8, spk, YT);
  // 3) per-edge local attention (dbuf, 2 blocks/CU)
  k_locatt<<<256, 256, 0, stream>>>(p1h, p2h, len, lwT);
  // 4-5) layer-1 aggregation + reduce (bf16 partials)
  k_wagg<<<dim3(8, 16, 2), 256, 0, stream>>>(lwT, YT, gw, spk, partH, 1);
  k_reduce1<<<dim3(16, 8), 256, 0, stream>>>(partH, x1part, x1h, x1T);
  // 6-7) layer-2 aggregation + reduce
  k_wagg<<<dim3(8, 16, 2), 256, 0, stream>>>(lwT, x1T, gw, spk, partH, 2);
  k_reduce2<<<512, 256, 0, stream>>>(partH, Z2h);
  // 8) final fused output GEMM (256 single-wave blocks)
  k_final<<<dim3(32, 8), 64, 0, stream>>>(Z2h, Wrel2T, x1h, Wroot2T, b2, out);
}